// Round 12
// baseline (149.287 us; speedup 1.0000x reference)
//
#include <hip/hip_runtime.h>
#include <hip/hip_bf16.h>

// DeepPM Transformer encoder layer (round 12): 5-kernel pipeline.
// Round-11 insight: GEMMs at K=256 were paying 16 barrier-drains/block in the
// 2-barrier BK=32 loop + 6 kernel boundaries. New one-shot-K structure:
// whole K=256 staged once into PADDED LDS (reg-staged; conflict-free), ONE
// barrier per block. FF2 (K=2048) = 8 such chunks, f32 accum -> split-K
// partials + reduce kernel eliminated entirely.
//  K1 [wc|qkv|cvt|lens]  K2 attn  K3 proj(os)  K4 ff1(os)  K5 ff2(os,NIT=8)
// B=8, L=1024, D=256, H=8 (DH=32), DFF=2048.

#define BB   8
#define LL   1024
#define DD   256
#define HHN  8
#define DHH  32
#define DFFN 2048

typedef __attribute__((ext_vector_type(8))) __bf16 bf16x8;
typedef __attribute__((ext_vector_type(4))) float f32x4;

__device__ inline bf16x8 cvt8(const float4 a, const float4 b) {
  bf16x8 o;
  o[0] = (__bf16)a.x; o[1] = (__bf16)a.y; o[2] = (__bf16)a.z; o[3] = (__bf16)a.w;
  o[4] = (__bf16)b.x; o[5] = (__bf16)b.y; o[6] = (__bf16)b.z; o[7] = (__bf16)b.w;
  return o;
}

// ---------------------------------------------------------------------------
// K1: fused preamble + QKV GEMM (unchanged from round 11).
//  [0,128):      Wc = proj_w@out_w (2 rows/block, LDS-staged, unroll-8), bc
//  [128,896):    QKV tile (BM=64 x BN=128), fp32 in (fused cvt), bf16 out
//  [896,1408):   cvt fp32->bf16 of {ff1_w, ff2_w}
//  1408:         lens[b] from mask
// ---------------------------------------------------------------------------
#define NCVT2 (DFFN * DD)  // 524288
#define NB_WC   128
#define NB_QKV  768
#define NB_CVT  512
#define BID_QKV  NB_WC
#define BID_CVT  (NB_WC + NB_QKV)
#define BID_LENS (BID_CVT + NB_CVT)
#define NB_TOTAL (BID_LENS + 1)

__global__ __launch_bounds__(256) void fused_pre_qkv(
    const float* __restrict__ src, const unsigned char* __restrict__ mb,
    const float* __restrict__ in_proj_w, const float* __restrict__ in_proj_b,
    const float* __restrict__ ff1_w, const float* __restrict__ ff2_w,
    const float* __restrict__ proj_w, const float* __restrict__ out_w,
    const float* __restrict__ proj_b, const float* __restrict__ out_b,
    __hip_bfloat16* __restrict__ qkv_bf, __hip_bfloat16* __restrict__ wff1_bf,
    __hip_bfloat16* __restrict__ wff2_bf, __hip_bfloat16* __restrict__ wc_bf,
    float* __restrict__ bc, int* __restrict__ lens) {
  __shared__ __bf16 As[2][64][32];
  __shared__ __bf16 Bs[2][128][32];
  __shared__ float red[256];
  __shared__ float pw[2][256];
  __shared__ int cnt8[BB];
  __shared__ int flag3f, flagNA;

  const int bid = blockIdx.x;
  const int tid = threadIdx.x;

  if (bid < NB_WC) {
    const int i0 = bid << 1;
    const int k = tid;
    pw[0][k] = proj_w[(size_t)i0 * DD + k];
    pw[1][k] = proj_w[(size_t)(i0 + 1) * DD + k];
    __syncthreads();
    float a0 = 0.f, a1 = 0.f;
#pragma unroll 8
    for (int n = 0; n < DD; ++n) {
      const float won = out_w[n * DD + k];
      a0 = fmaf(pw[0][n], won, a0);
      a1 = fmaf(pw[1][n], won, a1);
    }
    wc_bf[(size_t)i0 * DD + k] = (__hip_bfloat16)a0;
    wc_bf[(size_t)(i0 + 1) * DD + k] = (__hip_bfloat16)a1;
#pragma unroll
    for (int j = 0; j < 2; ++j) {
      red[k] = pw[j][k] * out_b[k];
      __syncthreads();
      for (int sft = 128; sft > 0; sft >>= 1) {
        if (k < sft) red[k] += red[k + sft];
        __syncthreads();
      }
      if (k == 0) bc[i0 + j] = proj_b[i0 + j] + red[0];
      __syncthreads();
    }
  } else if (bid < BID_CVT) {
    const int qb = bid - BID_QKV;
    const int x = qb % 6;
    const int y = qb / 6;
    const int c0 = x << 7;
    const int r0 = y << 6;
    const int w = tid >> 6;
    const int lane = tid & 63;
    const int c = lane & 15;
    const int hq = lane >> 4;
    const int h8 = hq << 3;
    const int wr = w >> 1, wc2 = w & 1;
    const int srow = tid >> 2;
    const int scol = (tid & 3) << 3;

    float4 ra[2], rb[2][2];
    auto LOADR = [&](int kt) {
      const int k0 = kt << 5;
      const float* ap = src + (size_t)(r0 + srow) * DD + k0 + scol;
      ra[0] = *(const float4*)ap;
      ra[1] = *(const float4*)(ap + 4);
#pragma unroll
      for (int ch = 0; ch < 2; ++ch) {
        const float* wp =
            in_proj_w + (size_t)(c0 + (ch << 6) + srow) * DD + k0 + scol;
        rb[ch][0] = *(const float4*)wp;
        rb[ch][1] = *(const float4*)(wp + 4);
      }
    };
    auto WRITEL = [&](int buf) {
      *(bf16x8*)&As[buf][srow][scol] = cvt8(ra[0], ra[1]);
#pragma unroll
      for (int ch = 0; ch < 2; ++ch)
        *(bf16x8*)&Bs[buf][(ch << 6) + srow][scol] = cvt8(rb[ch][0], rb[ch][1]);
    };

    f32x4 acc[2][4];
#pragma unroll
    for (int m = 0; m < 2; ++m)
#pragma unroll
      for (int n = 0; n < 4; ++n) acc[m][n] = (f32x4){0.f, 0.f, 0.f, 0.f};

    int buf = 0;
    LOADR(0);
    WRITEL(0);
    __syncthreads();
    for (int kt = 0; kt < 8; ++kt) {
      if (kt + 1 < 8) LOADR(kt + 1);
      bf16x8 af[2], bfr[4];
#pragma unroll
      for (int m = 0; m < 2; ++m)
        af[m] = *(const bf16x8*)&As[buf][wr * 32 + (m << 4) + c][h8];
#pragma unroll
      for (int n = 0; n < 4; ++n)
        bfr[n] = *(const bf16x8*)&Bs[buf][(wc2 << 6) + (n << 4) + c][h8];
#pragma unroll
      for (int m = 0; m < 2; ++m)
#pragma unroll
        for (int n = 0; n < 4; ++n)
          acc[m][n] = __builtin_amdgcn_mfma_f32_16x16x32_bf16(af[m], bfr[n],
                                                              acc[m][n], 0, 0, 0);
      if (kt + 1 < 8) WRITEL(buf ^ 1);
      __syncthreads();
      buf ^= 1;
    }

    float bv[4];
#pragma unroll
    for (int n = 0; n < 4; ++n)
      bv[n] = in_proj_b[c0 + (wc2 << 6) + (n << 4) + c];
#pragma unroll
    for (int m = 0; m < 2; ++m)
#pragma unroll
      for (int i = 0; i < 4; ++i) {
        const int gr = r0 + wr * 32 + (m << 4) + (hq << 2) + i;
#pragma unroll
        for (int n = 0; n < 4; ++n)
          qkv_bf[(size_t)gr * 768 + c0 + (wc2 << 6) + (n << 4) + c] =
              (__hip_bfloat16)(acc[m][n][i] + bv[n]);
      }
  } else if (bid < BID_LENS) {
    int i = (bid - BID_CVT) * 2048 + tid * 8;
    const float* s;
    __hip_bfloat16* d;
    if (i < NCVT2) { s = ff1_w; d = wff1_bf; }
    else { s = ff2_w; d = wff2_bf; i -= NCVT2; }
    const float4 a = *(const float4*)(s + i);
    const float4 b = *(const float4*)(s + i + 4);
    *(bf16x8*)(d + i) = cvt8(a, b);
  } else {
    if (tid == 0) { flag3f = 0; flagNA = 0; }
    if (tid < BB) cnt8[tid] = 0;
    __syncthreads();
    for (int i = tid; i < BB * LL; i += 256) {
      unsigned char v = mb[i];
      if (v) {
        if ((i & 3) == 3 && v == 0x3F) flag3f = 1;
        else if (i & 3) flagNA = 1;
      }
    }
    __syncthreads();
    const bool isfloat = (flag3f != 0);
    const bool isbool = (!isfloat) && (flagNA != 0);
    if (isbool) {
      for (int i = tid; i < BB * LL; i += 256)
        if (mb[i] == 0) atomicAdd(&cnt8[i >> 10], 1);
    } else {
      const int* mi = (const int*)mb;
      for (int i = tid; i < BB * LL; i += 256)
        if (mi[i] == 0) atomicAdd(&cnt8[i >> 10], 1);
    }
    __syncthreads();
    if (tid < BB) lens[tid] = cnt8[tid];
  }
}

// ---------------------------------------------------------------------------
// One-shot-K bf16 MFMA GEMM: C[M,N] = A @ W^T + epi, K = NIT*256.
// BM=32, BN=64, 4 waves (2x2, wave tile 16x32, MF=1 NF=2).
// Whole 256-wide K-chunk staged into PADDED LDS (stride 264: frag reads and
// staging writes conflict-free) via registers. NIT=1 -> ONE barrier total.
// NIT>1: loads for chunk t+1 issued before compute of t (latency hidden).
// EPI: 1 = +bias,gelu -> bf16; 2 = +bias+resid(f32) -> f32 AND bf16;
//      3 = +bias+resid(f32) -> f32, zero padded rows (writes zeros for dead
//          tiles -- it is the final output stage)
// ---------------------------------------------------------------------------
template <int EPI, int NIT>
__global__ __launch_bounds__(256) void gemm_os(
    const __hip_bfloat16* __restrict__ A, const __hip_bfloat16* __restrict__ W,
    const float* __restrict__ bias, const float* __restrict__ resid,
    float* __restrict__ Cf, __hip_bfloat16* __restrict__ Cb, const int N,
    const int* __restrict__ lens) {
  __shared__ __bf16 Al[32][264];
  __shared__ __bf16 Bl[64][264];

  const int tid = threadIdx.x;
  const int w = tid >> 6;
  const int lane = tid & 63;
  const int c = lane & 15;
  const int hq = lane >> 4;
  const int h8 = hq << 3;
  const int wr = w >> 1, wc = w & 1;
  const int c0 = blockIdx.x << 6;
  const int r0 = blockIdx.y << 5;
  const int K = NIT * 256;
  const int mylen = lens[r0 >> 10];

  if ((r0 & (LL - 1)) >= mylen) {
    if (EPI == 3) {
      const int rr = tid >> 3;
      const int cc = (tid & 7) << 3;
      const float4 z = {0.f, 0.f, 0.f, 0.f};
      *(float4*)&Cf[(size_t)(r0 + rr) * N + c0 + cc] = z;
      *(float4*)&Cf[(size_t)(r0 + rr) * N + c0 + cc + 4] = z;
    }
    return;
  }

  // staging map: A thread t -> row t>>3, 32-elem seg (t&7); B -> row t>>2,
  // 64-elem seg (t&3). Coalesced global reads; LDS writes conflict-free.
  const int ar = tid >> 3, asg = (tid & 7) << 5;
  const int br = tid >> 2, bsg = (tid & 3) << 6;

  bf16x8 ra[4], rb[8];
  auto LOADR = [&](int t) {
    const __hip_bfloat16* ap = A + (size_t)(r0 + ar) * K + t * 256 + asg;
#pragma unroll
    for (int j = 0; j < 4; ++j) ra[j] = *(const bf16x8*)(ap + j * 8);
    const __hip_bfloat16* bp = W + (size_t)(c0 + br) * K + t * 256 + bsg;
#pragma unroll
    for (int j = 0; j < 8; ++j) rb[j] = *(const bf16x8*)(bp + j * 8);
  };
  auto WRITEL = [&]() {
#pragma unroll
    for (int j = 0; j < 4; ++j) *(bf16x8*)&Al[ar][asg + j * 8] = ra[j];
#pragma unroll
    for (int j = 0; j < 8; ++j) *(bf16x8*)&Bl[br][bsg + j * 8] = rb[j];
  };

  f32x4 acc[2] = {{0.f, 0.f, 0.f, 0.f}, {0.f, 0.f, 0.f, 0.f}};

  LOADR(0);
  WRITEL();
  __syncthreads();
  for (int t = 0; t < NIT; ++t) {
    if (t + 1 < NIT) LOADR(t + 1);  // overlaps compute below
#pragma unroll
    for (int k0 = 0; k0 < 8; ++k0) {
      const bf16x8 af = *(const bf16x8*)&Al[wr * 16 + c][k0 * 32 + h8];
#pragma unroll
      for (int n = 0; n < 2; ++n) {
        const bf16x8 bf = *(const bf16x8*)&Bl[wc * 32 + (n << 4) + c][k0 * 32 + h8];
        acc[n] = __builtin_amdgcn_mfma_f32_16x16x32_bf16(af, bf, acc[n], 0, 0, 0);
      }
    }
    if (t + 1 < NIT) {
      __syncthreads();  // compute(t) done
      WRITEL();
      __syncthreads();  // chunk t+1 visible
    }
  }

  float bv[2];
#pragma unroll
  for (int n = 0; n < 2; ++n) bv[n] = bias[c0 + wc * 32 + (n << 4) + c];

#pragma unroll
  for (int i = 0; i < 4; ++i) {
    const int gr = r0 + wr * 16 + (hq << 2) + i;
    const bool zrow = (EPI == 3) && ((gr & (LL - 1)) >= mylen);
#pragma unroll
    for (int n = 0; n < 2; ++n) {
      const int gc = c0 + wc * 32 + (n << 4) + c;
      float v = acc[n][i] + bv[n];
      if (EPI == 1) v = 0.5f * v * (1.0f + erff(v * 0.70710678118654752f));
      if (EPI >= 2) v += resid[(size_t)gr * N + gc];
      if (EPI == 3 && zrow) v = 0.f;
      if (EPI >= 2) Cf[(size_t)gr * N + gc] = v;
      if (EPI != 3) Cb[(size_t)gr * N + gc] = (__hip_bfloat16)v;
    }
  }
}

// ---------------------------------------------------------------------------
// K2: MFMA bf16 flash attention (unchanged).
// ---------------------------------------------------------------------------
__global__ __launch_bounds__(256) void attn_fwd_mfma(
    const __hip_bfloat16* __restrict__ qkv, __hip_bfloat16* __restrict__ ctx,
    const int* __restrict__ lens) {
  __shared__ __bf16 Ks[2][64][56];
  __shared__ __bf16 Vt[2][32][66];
  __shared__ __bf16 Pl[4][16][72];

  const int tid = threadIdx.x;
  const int q0 = blockIdx.x << 6;
  const int hh = blockIdx.y;
  const int b = blockIdx.z;
  const int slen = lens[b];
  if (q0 >= slen) return;

  const int w = tid >> 6;
  const int lane = tid & 63;
  const int c = lane & 15;
  const int h = lane >> 4;
  const int h8 = h << 3;

  const float L2E = 1.44269504f;
  const float sf = (float)slen;
  const float cb = -7.0f * L2E;
  const float cd = (1.0f / sf) * L2E;
  const float qscale = 0.17677669529663689f * L2E;

  bf16x8 qf;
  {
    const int qrow = q0 + (w << 4) + c;
    const bf16x8 qraw =
        *(const bf16x8*)(qkv + (size_t)(b * LL + qrow) * 768 + hh * DHH + h8);
#pragma unroll
    for (int j = 0; j < 8; ++j) qf[j] = (__bf16)((float)qraw[j] * qscale);
  }

  f32x4 acc0 = {0.f, 0.f, 0.f, 0.f};
  f32x4 acc1 = {0.f, 0.f, 0.f, 0.f};
  float lsum[4] = {0.f, 0.f, 0.f, 0.f};

  const int skey = tid >> 2;
  const int sdg = (tid & 3) << 3;
  const int ntk = (slen + 63) >> 6;
  const int qg = q0 + (w << 4) + (h << 2);

  const __hip_bfloat16* kvbase = qkv + (size_t)b * LL * 768 + 256 + hh * DHH + sdg;

  bf16x8 kreg, vreg;
  {
    const __hip_bfloat16* kb = kvbase + (size_t)skey * 768;
    kreg = *(const bf16x8*)kb;
    vreg = *(const bf16x8*)(kb + 256);
    *(bf16x8*)&Ks[0][skey][sdg] = kreg;
#pragma unroll
    for (int j = 0; j < 8; ++j) Vt[0][sdg + j][skey] = vreg[j];
  }
  if (ntk > 1) {
    const __hip_bfloat16* kb = kvbase + (size_t)(64 + skey) * 768;
    kreg = *(const bf16x8*)kb;
    vreg = *(const bf16x8*)(kb + 256);
  }
  __syncthreads();

  for (int kt = 0; kt < ntk; ++kt) {
    const int p = kt & 1;
    const int kbase = kt << 6;

    f32x4 st[4];
    __builtin_amdgcn_s_setprio(1);
#pragma unroll
    for (int t = 0; t < 4; ++t) {
      const bf16x8 kf = *(const bf16x8*)&Ks[p][(t << 4) + c][h8];
      st[t] = __builtin_amdgcn_mfma_f32_16x16x32_bf16(
          qf, kf, (f32x4){0.f, 0.f, 0.f, 0.f}, 0, 0, 0);
    }
    __builtin_amdgcn_s_setprio(0);

    if (kbase + 64 <= slen) {
#pragma unroll
      for (int t = 0; t < 4; ++t) {
        const float kjf = (float)(kbase + (t << 4) + c);
#pragma unroll
        for (int i = 0; i < 4; ++i) {
          const float dist = fabsf((float)(qg + i) - kjf);
          const float pv = __builtin_amdgcn_exp2f(st[t][i] + cb - dist * cd);
          lsum[i] += pv;
          Pl[w][(h << 2) + i][c + (t << 4)] = (__bf16)pv;
        }
      }
    } else {
#pragma unroll
      for (int t = 0; t < 4; ++t) {
        const int kj = kbase + (t << 4) + c;
        const bool kvalid = kj < slen;
        const float kjf = (float)kj;
#pragma unroll
        for (int i = 0; i < 4; ++i) {
          const float dist = fabsf((float)(qg + i) - kjf);
          const float arg = kvalid ? (st[t][i] + cb - dist * cd) : -1e30f;
          const float pv = __builtin_amdgcn_exp2f(arg);
          lsum[i] += pv;
          Pl[w][(h << 2) + i][c + (t << 4)] = (__bf16)pv;
        }
      }
    }

    asm volatile("s_waitcnt lgkmcnt(0)" ::: "memory");

    __builtin_amdgcn_s_setprio(1);
#pragma unroll
    for (int n = 0; n < 2; ++n) {
      const bf16x8 pf = *(const bf16x8*)&Pl[w][c][h8 + (n << 5)];
      const uint32_t* v0p = (const uint32_t*)&Vt[p][c][h8 + (n << 5)];
      const uint32_t* v1p = (const uint32_t*)&Vt[p][16 + c][h8 + (n << 5)];
      union { uint32_t u[4]; bf16x8 v; } t0, t1;
#pragma unroll
      for (int j = 0; j < 4; ++j) { t0.u[j] = v0p[j]; t1.u[j] = v1p[j]; }
      acc0 = __builtin_amdgcn_mfma_f32_16x16x32_bf16(pf, t0.v, acc0, 0, 0, 0);
      acc1 = __builtin_amdgcn_mfma_f32_16x16x32_bf16(pf, t1.v, acc1, 0, 0, 0);
    }
    __builtin_amdgcn_s_setprio(0);

    if (kt + 1 < ntk) {
      *(bf16x8*)&Ks[p ^ 1][skey][sdg] = kreg;
#pragma unroll
      for (int j = 0; j < 8; ++j) Vt[p ^ 1][sdg + j][skey] = vreg[j];
      if (kt + 2 < ntk) {
        const __hip_bfloat16* kb = kvbase + (size_t)(((kt + 2) << 6) + skey) * 768;
        kreg = *(const bf16x8*)kb;
        vreg = *(const bf16x8*)(kb + 256);
      }
    }
    __syncthreads();
  }

#pragma unroll
  for (int i = 0; i < 4; ++i) {
    float l = lsum[i];
    l += __shfl_xor(l, 1);
    l += __shfl_xor(l, 2);
    l += __shfl_xor(l, 4);
    l += __shfl_xor(l, 8);
    const float il = 1.0f / l;
    __hip_bfloat16* op =
        ctx + (size_t)(b * LL + q0 + (w << 4) + (h << 2) + i) * 256 + hh * DHH;
    op[c] = (__hip_bfloat16)(acc0[i] * il);
    op[c + 16] = (__hip_bfloat16)(acc1[i] * il);
  }
}

// ---------------------------------------------------------------------------
extern "C" void kernel_launch(void* const* d_in, const int* in_sizes, int n_in,
                              void* d_out, int out_size, void* d_ws,
                              size_t ws_size, hipStream_t stream) {
  (void)in_sizes; (void)n_in; (void)out_size; (void)ws_size;
  const float* src = (const float*)d_in[0];
  const unsigned char* mask = (const unsigned char*)d_in[1];
  const float* in_proj_w = (const float*)d_in[2];
  const float* in_proj_b = (const float*)d_in[3];
  const float* out_w = (const float*)d_in[4];
  const float* out_b = (const float*)d_in[5];
  const float* proj_w = (const float*)d_in[6];
  const float* proj_b = (const float*)d_in[7];
  const float* ff1_w = (const float*)d_in[8];
  const float* ff1_b = (const float*)d_in[9];
  const float* ff2_w = (const float*)d_in[10];
  const float* ff2_b = (const float*)d_in[11];
  float* out = (float*)d_out;

  const int M = BB * LL;  // 8192
  char* p = (char*)d_ws;
  __hip_bfloat16* qkv_bf = (__hip_bfloat16*)p; p += (size_t)M * 768 * 2;
  __hip_bfloat16* ctx_bf = (__hip_bfloat16*)p; p += (size_t)M * 256 * 2;
  float* hbuf_f = (float*)p;                    p += (size_t)M * 256 * 4;
  __hip_bfloat16* hbuf_bf = (__hip_bfloat16*)p; p += (size_t)M * 256 * 2;
  __hip_bfloat16* ff1o_bf = (__hip_bfloat16*)p; p += (size_t)M * 2048 * 2;
  __hip_bfloat16* wff1_bf = (__hip_bfloat16*)p; p += (size_t)2048 * 256 * 2;
  __hip_bfloat16* wff2_bf = (__hip_bfloat16*)p; p += (size_t)256 * 2048 * 2;
  __hip_bfloat16* wc_bf = (__hip_bfloat16*)p;   p += (size_t)256 * 256 * 2;
  float* bc = (float*)p;                        p += 256 * 4;
  int* lens = (int*)p;                          p += 256;

  // K1: Wc first (longest serial chain), then QKV tiles, cvt, lens
  fused_pre_qkv<<<NB_TOTAL, 256, 0, stream>>>(
      src, mask, in_proj_w, in_proj_b, ff1_w, ff2_w, proj_w, out_w, proj_b,
      out_b, qkv_bf, wff1_bf, wff2_bf, wc_bf, bc, lens);

  // K2: attention
  attn_fwd_mfma<<<dim3(LL / 64, HHN, BB), 256, 0, stream>>>(qkv_bf, ctx_bf, lens);

  // K3: hbuf = src + ctx @ Wc^T + bc   (one-shot K=256)
  gemm_os<2, 1><<<dim3(4, 256), 256, 0, stream>>>(
      ctx_bf, wc_bf, bc, src, hbuf_f, hbuf_bf, DD, lens);

  // K4: ff1o = gelu(hbuf @ ff1^T + b)  (one-shot K=256)
  gemm_os<1, 1><<<dim3(32, 256), 256, 0, stream>>>(
      hbuf_bf, wff1_bf, ff1_b, nullptr, nullptr, ff1o_bf, DFFN, lens);

  // K5: out = hbuf + ff1o @ ff2^T + b, zero padded rows (K=2048, 8 chunks)
  gemm_os<3, 8><<<dim3(4, 256), 256, 0, stream>>>(
      ff1o_bf, wff2_bf, ff2_b, hbuf_f, out, nullptr, DD, lens);
}

// Round 13
// 117.583 us; speedup vs baseline: 1.2696x; 1.2696x over previous
//
#include <hip/hip_runtime.h>
#include <hip/hip_bf16.h>

// DeepPM Transformer encoder layer (round 13): 5-kernel pipeline.
// Round-12 post-mortem: one-shot-K LDS layout (stride 264 = 132 words ≡ 4 mod
// 32) caused 8-way bank conflicts on frag reads (8.7M conflict cycles) + 3
// blocks/CU -> regression. Reverted to the proven [row][32] BK=32 structure.
// This round's single change: FF2 = plain full-K gemm_bf16<3,64,64> (K=2048,
// 16KB LDS -> deep co-residency overlaps the 64 barrier drains) replacing
// split-K partials + reduce kernel (one less boundary, 34MB less traffic,
// full-f32 K accumulation).
//  K1 [wc|qkv|cvt|lens]  K2 attn  K3 proj(64x64)  K4 ff1(128x128)  K5 ff2(64x64,K=2048)
// B=8, L=1024, D=256, H=8 (DH=32), DFF=2048.

#define BB   8
#define LL   1024
#define DD   256
#define HHN  8
#define DHH  32
#define DFFN 2048

typedef __attribute__((ext_vector_type(8))) __bf16 bf16x8;
typedef __attribute__((ext_vector_type(4))) float f32x4;

__device__ inline void gload16(const void* g, void* l) {
  __builtin_amdgcn_global_load_lds(
      (const __attribute__((address_space(1))) void*)g,
      (__attribute__((address_space(3))) void*)l, 16, 0, 0);
}

__device__ inline bf16x8 cvt8(const float4 a, const float4 b) {
  bf16x8 o;
  o[0] = (__bf16)a.x; o[1] = (__bf16)a.y; o[2] = (__bf16)a.z; o[3] = (__bf16)a.w;
  o[4] = (__bf16)b.x; o[5] = (__bf16)b.y; o[6] = (__bf16)b.z; o[7] = (__bf16)b.w;
  return o;
}

// ---------------------------------------------------------------------------
// K1: fused preamble + QKV GEMM. Roles by blockIdx.x (Wc first: longest
// serial chain starts earliest):
//  [0,128):      Wc = proj_w@out_w (2 rows/block, LDS-staged, unroll-8), bc
//  [128,896):    QKV tile (BM=64 x BN=128), fp32 in (fused cvt), bf16 out
//  [896,1408):   cvt fp32->bf16 of {ff1_w, ff2_w}
//  1408:         lens[b] from mask
// ---------------------------------------------------------------------------
#define NCVT2 (DFFN * DD)  // 524288
#define NB_WC   128
#define NB_QKV  768
#define NB_CVT  512
#define BID_QKV  NB_WC
#define BID_CVT  (NB_WC + NB_QKV)
#define BID_LENS (BID_CVT + NB_CVT)
#define NB_TOTAL (BID_LENS + 1)

__global__ __launch_bounds__(256) void fused_pre_qkv(
    const float* __restrict__ src, const unsigned char* __restrict__ mb,
    const float* __restrict__ in_proj_w, const float* __restrict__ in_proj_b,
    const float* __restrict__ ff1_w, const float* __restrict__ ff2_w,
    const float* __restrict__ proj_w, const float* __restrict__ out_w,
    const float* __restrict__ proj_b, const float* __restrict__ out_b,
    __hip_bfloat16* __restrict__ qkv_bf, __hip_bfloat16* __restrict__ wff1_bf,
    __hip_bfloat16* __restrict__ wff2_bf, __hip_bfloat16* __restrict__ wc_bf,
    float* __restrict__ bc, int* __restrict__ lens) {
  __shared__ __bf16 As[2][64][32];
  __shared__ __bf16 Bs[2][128][32];
  __shared__ float red[256];
  __shared__ float pw[2][256];
  __shared__ int cnt8[BB];
  __shared__ int flag3f, flagNA;

  const int bid = blockIdx.x;
  const int tid = threadIdx.x;

  if (bid < NB_WC) {
    const int i0 = bid << 1;
    const int k = tid;
    pw[0][k] = proj_w[(size_t)i0 * DD + k];
    pw[1][k] = proj_w[(size_t)(i0 + 1) * DD + k];
    __syncthreads();
    float a0 = 0.f, a1 = 0.f;
#pragma unroll 8
    for (int n = 0; n < DD; ++n) {
      const float won = out_w[n * DD + k];
      a0 = fmaf(pw[0][n], won, a0);
      a1 = fmaf(pw[1][n], won, a1);
    }
    wc_bf[(size_t)i0 * DD + k] = (__hip_bfloat16)a0;
    wc_bf[(size_t)(i0 + 1) * DD + k] = (__hip_bfloat16)a1;
#pragma unroll
    for (int j = 0; j < 2; ++j) {
      red[k] = pw[j][k] * out_b[k];
      __syncthreads();
      for (int sft = 128; sft > 0; sft >>= 1) {
        if (k < sft) red[k] += red[k + sft];
        __syncthreads();
      }
      if (k == 0) bc[i0 + j] = proj_b[i0 + j] + red[0];
      __syncthreads();
    }
  } else if (bid < BID_CVT) {
    const int qb = bid - BID_QKV;
    const int x = qb % 6;
    const int y = qb / 6;
    const int c0 = x << 7;
    const int r0 = y << 6;
    const int w = tid >> 6;
    const int lane = tid & 63;
    const int c = lane & 15;
    const int hq = lane >> 4;
    const int h8 = hq << 3;
    const int wr = w >> 1, wc2 = w & 1;
    const int srow = tid >> 2;
    const int scol = (tid & 3) << 3;

    float4 ra[2], rb[2][2];
    auto LOADR = [&](int kt) {
      const int k0 = kt << 5;
      const float* ap = src + (size_t)(r0 + srow) * DD + k0 + scol;
      ra[0] = *(const float4*)ap;
      ra[1] = *(const float4*)(ap + 4);
#pragma unroll
      for (int ch = 0; ch < 2; ++ch) {
        const float* wp =
            in_proj_w + (size_t)(c0 + (ch << 6) + srow) * DD + k0 + scol;
        rb[ch][0] = *(const float4*)wp;
        rb[ch][1] = *(const float4*)(wp + 4);
      }
    };
    auto WRITEL = [&](int buf) {
      *(bf16x8*)&As[buf][srow][scol] = cvt8(ra[0], ra[1]);
#pragma unroll
      for (int ch = 0; ch < 2; ++ch)
        *(bf16x8*)&Bs[buf][(ch << 6) + srow][scol] = cvt8(rb[ch][0], rb[ch][1]);
    };

    f32x4 acc[2][4];
#pragma unroll
    for (int m = 0; m < 2; ++m)
#pragma unroll
      for (int n = 0; n < 4; ++n) acc[m][n] = (f32x4){0.f, 0.f, 0.f, 0.f};

    int buf = 0;
    LOADR(0);
    WRITEL(0);
    __syncthreads();
    for (int kt = 0; kt < 8; ++kt) {
      if (kt + 1 < 8) LOADR(kt + 1);
      bf16x8 af[2], bfr[4];
#pragma unroll
      for (int m = 0; m < 2; ++m)
        af[m] = *(const bf16x8*)&As[buf][wr * 32 + (m << 4) + c][h8];
#pragma unroll
      for (int n = 0; n < 4; ++n)
        bfr[n] = *(const bf16x8*)&Bs[buf][(wc2 << 6) + (n << 4) + c][h8];
#pragma unroll
      for (int m = 0; m < 2; ++m)
#pragma unroll
        for (int n = 0; n < 4; ++n)
          acc[m][n] = __builtin_amdgcn_mfma_f32_16x16x32_bf16(af[m], bfr[n],
                                                              acc[m][n], 0, 0, 0);
      if (kt + 1 < 8) WRITEL(buf ^ 1);
      __syncthreads();
      buf ^= 1;
    }

    float bv[4];
#pragma unroll
    for (int n = 0; n < 4; ++n)
      bv[n] = in_proj_b[c0 + (wc2 << 6) + (n << 4) + c];
#pragma unroll
    for (int m = 0; m < 2; ++m)
#pragma unroll
      for (int i = 0; i < 4; ++i) {
        const int gr = r0 + wr * 32 + (m << 4) + (hq << 2) + i;
#pragma unroll
        for (int n = 0; n < 4; ++n)
          qkv_bf[(size_t)gr * 768 + c0 + (wc2 << 6) + (n << 4) + c] =
              (__hip_bfloat16)(acc[m][n][i] + bv[n]);
      }
  } else if (bid < BID_LENS) {
    int i = (bid - BID_CVT) * 2048 + tid * 8;
    const float* s;
    __hip_bfloat16* d;
    if (i < NCVT2) { s = ff1_w; d = wff1_bf; }
    else { s = ff2_w; d = wff2_bf; i -= NCVT2; }
    const float4 a = *(const float4*)(s + i);
    const float4 b = *(const float4*)(s + i + 4);
    *(bf16x8*)(d + i) = cvt8(a, b);
  } else {
    if (tid == 0) { flag3f = 0; flagNA = 0; }
    if (tid < BB) cnt8[tid] = 0;
    __syncthreads();
    for (int i = tid; i < BB * LL; i += 256) {
      unsigned char v = mb[i];
      if (v) {
        if ((i & 3) == 3 && v == 0x3F) flag3f = 1;
        else if (i & 3) flagNA = 1;
      }
    }
    __syncthreads();
    const bool isfloat = (flag3f != 0);
    const bool isbool = (!isfloat) && (flagNA != 0);
    if (isbool) {
      for (int i = tid; i < BB * LL; i += 256)
        if (mb[i] == 0) atomicAdd(&cnt8[i >> 10], 1);
    } else {
      const int* mi = (const int*)mb;
      for (int i = tid; i < BB * LL; i += 256)
        if (mi[i] == 0) atomicAdd(&cnt8[i >> 10], 1);
    }
    __syncthreads();
    if (tid < BB) lens[tid] = cnt8[tid];
  }
}

// ---------------------------------------------------------------------------
// Generalized bf16 MFMA NT GEMM: C = A @ W^T + epi. 4 waves (2x2), BK=32.
// EPI: 1 = +bias,gelu -> bf16; 2 = +bias+resid(f32) -> f32 AND bf16;
//      3 = +bias+resid(f32) -> f32 only, zero padded rows (final output:
//          dead tiles write zeros).
// ---------------------------------------------------------------------------
template <int EPI, int BM, int BN>
__global__ __launch_bounds__(256) void gemm_bf16(
    const __hip_bfloat16* __restrict__ A, const __hip_bfloat16* __restrict__ W,
    const float* __restrict__ bias, const float* __restrict__ resid,
    float* __restrict__ Cf, __hip_bfloat16* __restrict__ Cb, const int M,
    const int N, const int K, const int* __restrict__ lens) {
  constexpr int MF = BM / 32;
  constexpr int NF = BN / 32;
  constexpr int CHA = BM / 64;
  constexpr int CHB = BN / 64;
  __shared__ __bf16 As[2][BM][32];
  __shared__ __bf16 Bs[2][BN][32];

  const int tid = threadIdx.x;
  const int w = tid >> 6;
  const int lane = tid & 63;
  const int c = lane & 15;
  const int hq = lane >> 4;
  const int h8 = hq << 3;
  const int wr = w >> 1, wc = w & 1;
  const int c0 = blockIdx.x * BN;
  const int r0 = blockIdx.y * BM;
  const int mylen = lens[r0 >> 10];

  if ((r0 & (LL - 1)) >= mylen) {
    if (EPI == 3) {
      // final output stage: padded rows must be written as zeros
      constexpr int NF4 = BM * BN / 4 / 256;  // float4s per thread
#pragma unroll
      for (int k = 0; k < NF4; ++k) {
        const int f4 = k * 256 + tid;
        const int rr = f4 / (BN / 4);
        const int cc = (f4 % (BN / 4)) << 2;
        *(float4*)&Cf[(size_t)(r0 + rr) * N + c0 + cc] =
            (float4){0.f, 0.f, 0.f, 0.f};
      }
    }
    return;
  }

  const int srow = tid >> 2;
  const int scol = (tid & 3) << 3;

  auto STAGE = [&](int buf, int kt) {
    const int k0 = kt << 5;
#pragma unroll
    for (int ch = 0; ch < CHA; ++ch)
      gload16(A + (size_t)(r0 + (ch << 6) + srow) * K + k0 + scol,
              &As[buf][(ch << 6) + (w << 4)][0]);
#pragma unroll
    for (int ch = 0; ch < CHB; ++ch)
      gload16(W + (size_t)(c0 + (ch << 6) + srow) * K + k0 + scol,
              &Bs[buf][(ch << 6) + (w << 4)][0]);
  };

  f32x4 acc[MF][NF];
#pragma unroll
  for (int m = 0; m < MF; ++m)
#pragma unroll
    for (int n = 0; n < NF; ++n) acc[m][n] = (f32x4){0.f, 0.f, 0.f, 0.f};

  const int nkt = K >> 5;
  int buf = 0;
  STAGE(0, 0);
  __syncthreads();
  for (int kt = 0; kt < nkt; ++kt) {
    if (kt + 1 < nkt) STAGE(buf ^ 1, kt + 1);
    bf16x8 af[MF], bfr[NF];
#pragma unroll
    for (int m = 0; m < MF; ++m)
      af[m] = *(const bf16x8*)&As[buf][wr * (MF * 16) + (m << 4) + c][h8];
#pragma unroll
    for (int n = 0; n < NF; ++n)
      bfr[n] = *(const bf16x8*)&Bs[buf][wc * (NF * 16) + (n << 4) + c][h8];
#pragma unroll
    for (int m = 0; m < MF; ++m)
#pragma unroll
      for (int n = 0; n < NF; ++n)
        acc[m][n] =
            __builtin_amdgcn_mfma_f32_16x16x32_bf16(af[m], bfr[n], acc[m][n], 0, 0, 0);
    __syncthreads();
    buf ^= 1;
  }

  float bv[NF];
#pragma unroll
  for (int n = 0; n < NF; ++n) bv[n] = bias[c0 + wc * (NF * 16) + (n << 4) + c];

#pragma unroll
  for (int m = 0; m < MF; ++m) {
#pragma unroll
    for (int i = 0; i < 4; ++i) {
      const int gr = r0 + wr * (MF * 16) + (m << 4) + (hq << 2) + i;
      const bool zrow = (EPI == 3) && ((gr & (LL - 1)) >= mylen);
#pragma unroll
      for (int n = 0; n < NF; ++n) {
        const int gc = c0 + wc * (NF * 16) + (n << 4) + c;
        float v = acc[m][n][i] + bv[n];
        if (EPI == 1) v = 0.5f * v * (1.0f + erff(v * 0.70710678118654752f));
        if (EPI >= 2) v += resid[(size_t)gr * N + gc];
        if (EPI == 3 && zrow) v = 0.f;
        if (EPI >= 2) Cf[(size_t)gr * N + gc] = v;
        if (EPI != 3) Cb[(size_t)gr * N + gc] = (__hip_bfloat16)v;
      }
    }
  }
}

// ---------------------------------------------------------------------------
// K2: MFMA bf16 flash attention (unchanged, proven).
// ---------------------------------------------------------------------------
__global__ __launch_bounds__(256) void attn_fwd_mfma(
    const __hip_bfloat16* __restrict__ qkv, __hip_bfloat16* __restrict__ ctx,
    const int* __restrict__ lens) {
  __shared__ __bf16 Ks[2][64][56];
  __shared__ __bf16 Vt[2][32][66];
  __shared__ __bf16 Pl[4][16][72];

  const int tid = threadIdx.x;
  const int q0 = blockIdx.x << 6;
  const int hh = blockIdx.y;
  const int b = blockIdx.z;
  const int slen = lens[b];
  if (q0 >= slen) return;

  const int w = tid >> 6;
  const int lane = tid & 63;
  const int c = lane & 15;
  const int h = lane >> 4;
  const int h8 = h << 3;

  const float L2E = 1.44269504f;
  const float sf = (float)slen;
  const float cb = -7.0f * L2E;
  const float cd = (1.0f / sf) * L2E;
  const float qscale = 0.17677669529663689f * L2E;

  bf16x8 qf;
  {
    const int qrow = q0 + (w << 4) + c;
    const bf16x8 qraw =
        *(const bf16x8*)(qkv + (size_t)(b * LL + qrow) * 768 + hh * DHH + h8);
#pragma unroll
    for (int j = 0; j < 8; ++j) qf[j] = (__bf16)((float)qraw[j] * qscale);
  }

  f32x4 acc0 = {0.f, 0.f, 0.f, 0.f};
  f32x4 acc1 = {0.f, 0.f, 0.f, 0.f};
  float lsum[4] = {0.f, 0.f, 0.f, 0.f};

  const int skey = tid >> 2;
  const int sdg = (tid & 3) << 3;
  const int ntk = (slen + 63) >> 6;
  const int qg = q0 + (w << 4) + (h << 2);

  const __hip_bfloat16* kvbase = qkv + (size_t)b * LL * 768 + 256 + hh * DHH + sdg;

  bf16x8 kreg, vreg;
  {
    const __hip_bfloat16* kb = kvbase + (size_t)skey * 768;
    kreg = *(const bf16x8*)kb;
    vreg = *(const bf16x8*)(kb + 256);
    *(bf16x8*)&Ks[0][skey][sdg] = kreg;
#pragma unroll
    for (int j = 0; j < 8; ++j) Vt[0][sdg + j][skey] = vreg[j];
  }
  if (ntk > 1) {
    const __hip_bfloat16* kb = kvbase + (size_t)(64 + skey) * 768;
    kreg = *(const bf16x8*)kb;
    vreg = *(const bf16x8*)(kb + 256);
  }
  __syncthreads();

  for (int kt = 0; kt < ntk; ++kt) {
    const int p = kt & 1;
    const int kbase = kt << 6;

    f32x4 st[4];
    __builtin_amdgcn_s_setprio(1);
#pragma unroll
    for (int t = 0; t < 4; ++t) {
      const bf16x8 kf = *(const bf16x8*)&Ks[p][(t << 4) + c][h8];
      st[t] = __builtin_amdgcn_mfma_f32_16x16x32_bf16(
          qf, kf, (f32x4){0.f, 0.f, 0.f, 0.f}, 0, 0, 0);
    }
    __builtin_amdgcn_s_setprio(0);

    if (kbase + 64 <= slen) {
#pragma unroll
      for (int t = 0; t < 4; ++t) {
        const float kjf = (float)(kbase + (t << 4) + c);
#pragma unroll
        for (int i = 0; i < 4; ++i) {
          const float dist = fabsf((float)(qg + i) - kjf);
          const float pv = __builtin_amdgcn_exp2f(st[t][i] + cb - dist * cd);
          lsum[i] += pv;
          Pl[w][(h << 2) + i][c + (t << 4)] = (__bf16)pv;
        }
      }
    } else {
#pragma unroll
      for (int t = 0; t < 4; ++t) {
        const int kj = kbase + (t << 4) + c;
        const bool kvalid = kj < slen;
        const float kjf = (float)kj;
#pragma unroll
        for (int i = 0; i < 4; ++i) {
          const float dist = fabsf((float)(qg + i) - kjf);
          const float arg = kvalid ? (st[t][i] + cb - dist * cd) : -1e30f;
          const float pv = __builtin_amdgcn_exp2f(arg);
          lsum[i] += pv;
          Pl[w][(h << 2) + i][c + (t << 4)] = (__bf16)pv;
        }
      }
    }

    asm volatile("s_waitcnt lgkmcnt(0)" ::: "memory");

    __builtin_amdgcn_s_setprio(1);
#pragma unroll
    for (int n = 0; n < 2; ++n) {
      const bf16x8 pf = *(const bf16x8*)&Pl[w][c][h8 + (n << 5)];
      const uint32_t* v0p = (const uint32_t*)&Vt[p][c][h8 + (n << 5)];
      const uint32_t* v1p = (const uint32_t*)&Vt[p][16 + c][h8 + (n << 5)];
      union { uint32_t u[4]; bf16x8 v; } t0, t1;
#pragma unroll
      for (int j = 0; j < 4; ++j) { t0.u[j] = v0p[j]; t1.u[j] = v1p[j]; }
      acc0 = __builtin_amdgcn_mfma_f32_16x16x32_bf16(pf, t0.v, acc0, 0, 0, 0);
      acc1 = __builtin_amdgcn_mfma_f32_16x16x32_bf16(pf, t1.v, acc1, 0, 0, 0);
    }
    __builtin_amdgcn_s_setprio(0);

    if (kt + 1 < ntk) {
      *(bf16x8*)&Ks[p ^ 1][skey][sdg] = kreg;
#pragma unroll
      for (int j = 0; j < 8; ++j) Vt[p ^ 1][sdg + j][skey] = vreg[j];
      if (kt + 2 < ntk) {
        const __hip_bfloat16* kb = kvbase + (size_t)(((kt + 2) << 6) + skey) * 768;
        kreg = *(const bf16x8*)kb;
        vreg = *(const bf16x8*)(kb + 256);
      }
    }
    __syncthreads();
  }

#pragma unroll
  for (int i = 0; i < 4; ++i) {
    float l = lsum[i];
    l += __shfl_xor(l, 1);
    l += __shfl_xor(l, 2);
    l += __shfl_xor(l, 4);
    l += __shfl_xor(l, 8);
    const float il = 1.0f / l;
    __hip_bfloat16* op =
        ctx + (size_t)(b * LL + q0 + (w << 4) + (h << 2) + i) * 256 + hh * DHH;
    op[c] = (__hip_bfloat16)(acc0[i] * il);
    op[c + 16] = (__hip_bfloat16)(acc1[i] * il);
  }
}

// ---------------------------------------------------------------------------
extern "C" void kernel_launch(void* const* d_in, const int* in_sizes, int n_in,
                              void* d_out, int out_size, void* d_ws,
                              size_t ws_size, hipStream_t stream) {
  (void)in_sizes; (void)n_in; (void)out_size; (void)ws_size;
  const float* src = (const float*)d_in[0];
  const unsigned char* mask = (const unsigned char*)d_in[1];
  const float* in_proj_w = (const float*)d_in[2];
  const float* in_proj_b = (const float*)d_in[3];
  const float* out_w = (const float*)d_in[4];
  const float* out_b = (const float*)d_in[5];
  const float* proj_w = (const float*)d_in[6];
  const float* proj_b = (const float*)d_in[7];
  const float* ff1_w = (const float*)d_in[8];
  const float* ff1_b = (const float*)d_in[9];
  const float* ff2_w = (const float*)d_in[10];
  const float* ff2_b = (const float*)d_in[11];
  float* out = (float*)d_out;

  const int M = BB * LL;  // 8192
  char* p = (char*)d_ws;
  __hip_bfloat16* qkv_bf = (__hip_bfloat16*)p; p += (size_t)M * 768 * 2;
  __hip_bfloat16* ctx_bf = (__hip_bfloat16*)p; p += (size_t)M * 256 * 2;
  float* hbuf_f = (float*)p;                    p += (size_t)M * 256 * 4;
  __hip_bfloat16* hbuf_bf = (__hip_bfloat16*)p; p += (size_t)M * 256 * 2;
  __hip_bfloat16* ff1o_bf = (__hip_bfloat16*)p; p += (size_t)M * 2048 * 2;
  __hip_bfloat16* wff1_bf = (__hip_bfloat16*)p; p += (size_t)2048 * 256 * 2;
  __hip_bfloat16* wff2_bf = (__hip_bfloat16*)p; p += (size_t)256 * 2048 * 2;
  __hip_bfloat16* wc_bf = (__hip_bfloat16*)p;   p += (size_t)256 * 256 * 2;
  float* bc = (float*)p;                        p += 256 * 4;
  int* lens = (int*)p;                          p += 256;

  // K1: Wc first (longest serial chain), then QKV tiles, cvt, lens
  fused_pre_qkv<<<NB_TOTAL, 256, 0, stream>>>(
      src, mask, in_proj_w, in_proj_b, ff1_w, ff2_w, proj_w, out_w, proj_b,
      out_b, qkv_bf, wff1_bf, wff2_bf, wc_bf, bc, lens);

  // K2: attention
  attn_fwd_mfma<<<dim3(LL / 64, HHN, BB), 256, 0, stream>>>(qkv_bf, ctx_bf, lens);

  // K3: hbuf = src + ctx @ Wc^T + bc  (BM=64, BN=64, grid 512)
  gemm_bf16<2, 64, 64><<<dim3(4, 128), 256, 0, stream>>>(
      ctx_bf, wc_bf, bc, src, hbuf_f, hbuf_bf, M, 256, 256, lens);

  // K4: ff1o = gelu(hbuf @ ff1^T + b)  (BM=128, BN=128)
  gemm_bf16<1, 128, 128><<<dim3(16, 64), 256, 0, stream>>>(
      hbuf_bf, wff1_bf, ff1_b, nullptr, nullptr, ff1o_bf, M, 2048, 256, lens);

  // K5: out = hbuf + ff1o @ ff2^T + b, zero padded rows (full K=2048,
  // BM=64/BN=64, 16KB LDS -> deep co-residency overlaps barrier drains)
  gemm_bf16<3, 64, 64><<<dim3(4, 128), 256, 0, stream>>>(
      ff1o_bf, wff2_bf, ff2_b, hbuf_f, out, nullptr, M, 256, 2048, lens);
}

// Round 14
// 115.648 us; speedup vs baseline: 1.2909x; 1.0167x over previous
//
#include <hip/hip_runtime.h>
#include <hip/hip_bf16.h>

// DeepPM Transformer encoder layer (round 14): 6-kernel pipeline.
// Round-13 post-mortem: full-K FF2 (−1 boundary, +64 serial drains) lost 3.4us
// vs split-K — reverted to round-11's proven split-K x4 + reduce.
// New this round: weight-cvt roles migrated OUT of K1 into K3/K4 (they fully
// overlap proj/ff1 there; stream order guarantees completion before use), so
// K1's QKV role runs uncontended.
//  K1 [wc|qkv|lens]  K2 attn  K3 [proj|cvt ff1_w]  K4 [ff1|cvt ff2_w]
//  K5 ff2 split-K x4  K6 ff2 reduce
// B=8, L=1024, D=256, H=8 (DH=32), DFF=2048.

#define BB   8
#define LL   1024
#define DD   256
#define HHN  8
#define DHH  32
#define DFFN 2048

typedef __attribute__((ext_vector_type(8))) __bf16 bf16x8;
typedef __attribute__((ext_vector_type(4))) float f32x4;

__device__ inline void gload16(const void* g, void* l) {
  __builtin_amdgcn_global_load_lds(
      (const __attribute__((address_space(1))) void*)g,
      (__attribute__((address_space(3))) void*)l, 16, 0, 0);
}

__device__ inline bf16x8 cvt8(const float4 a, const float4 b) {
  bf16x8 o;
  o[0] = (__bf16)a.x; o[1] = (__bf16)a.y; o[2] = (__bf16)a.z; o[3] = (__bf16)a.w;
  o[4] = (__bf16)b.x; o[5] = (__bf16)b.y; o[6] = (__bf16)b.z; o[7] = (__bf16)b.w;
  return o;
}

// 256-thread block converts 2048 fp32 -> bf16 at element offset i0.
__device__ inline void cvt_block(const float* __restrict__ s,
                                 __hip_bfloat16* __restrict__ d, int i0) {
  const int i = i0 + threadIdx.x * 8;
  const float4 a = *(const float4*)(s + i);
  const float4 b = *(const float4*)(s + i + 4);
  *(bf16x8*)(d + i) = cvt8(a, b);
}

// ---------------------------------------------------------------------------
// K1: Wc + QKV + lens (cvt roles moved to K3/K4).
//  [0,128):    Wc = proj_w@out_w (2 rows/block, LDS-staged, unroll-8), bc
//  [128,896):  QKV tile (BM=64 x BN=128), fp32 in (fused cvt), bf16 out
//  896:        lens[b] from mask
// ---------------------------------------------------------------------------
#define NB_WC   128
#define NB_QKV  768
#define BID_QKV  NB_WC               // 128
#define BID_LENS (NB_WC + NB_QKV)    // 896
#define NB_K1    (BID_LENS + 1)      // 897

__global__ __launch_bounds__(256) void fused_pre_qkv(
    const float* __restrict__ src, const unsigned char* __restrict__ mb,
    const float* __restrict__ in_proj_w, const float* __restrict__ in_proj_b,
    const float* __restrict__ proj_w, const float* __restrict__ out_w,
    const float* __restrict__ proj_b, const float* __restrict__ out_b,
    __hip_bfloat16* __restrict__ qkv_bf, __hip_bfloat16* __restrict__ wc_bf,
    float* __restrict__ bc, int* __restrict__ lens) {
  __shared__ __bf16 As[2][64][32];
  __shared__ __bf16 Bs[2][128][32];
  __shared__ float red[256];
  __shared__ float pw[2][256];
  __shared__ int cnt8[BB];
  __shared__ int flag3f, flagNA;

  const int bid = blockIdx.x;
  const int tid = threadIdx.x;

  if (bid < NB_WC) {
    const int i0 = bid << 1;
    const int k = tid;
    pw[0][k] = proj_w[(size_t)i0 * DD + k];
    pw[1][k] = proj_w[(size_t)(i0 + 1) * DD + k];
    __syncthreads();
    float a0 = 0.f, a1 = 0.f;
#pragma unroll 8
    for (int n = 0; n < DD; ++n) {
      const float won = out_w[n * DD + k];
      a0 = fmaf(pw[0][n], won, a0);
      a1 = fmaf(pw[1][n], won, a1);
    }
    wc_bf[(size_t)i0 * DD + k] = (__hip_bfloat16)a0;
    wc_bf[(size_t)(i0 + 1) * DD + k] = (__hip_bfloat16)a1;
#pragma unroll
    for (int j = 0; j < 2; ++j) {
      red[k] = pw[j][k] * out_b[k];
      __syncthreads();
      for (int sft = 128; sft > 0; sft >>= 1) {
        if (k < sft) red[k] += red[k + sft];
        __syncthreads();
      }
      if (k == 0) bc[i0 + j] = proj_b[i0 + j] + red[0];
      __syncthreads();
    }
  } else if (bid < BID_LENS) {
    const int qb = bid - BID_QKV;
    const int x = qb % 6;
    const int y = qb / 6;
    const int c0 = x << 7;
    const int r0 = y << 6;
    const int w = tid >> 6;
    const int lane = tid & 63;
    const int c = lane & 15;
    const int hq = lane >> 4;
    const int h8 = hq << 3;
    const int wr = w >> 1, wc2 = w & 1;
    const int srow = tid >> 2;
    const int scol = (tid & 3) << 3;

    float4 ra[2], rb[2][2];
    auto LOADR = [&](int kt) {
      const int k0 = kt << 5;
      const float* ap = src + (size_t)(r0 + srow) * DD + k0 + scol;
      ra[0] = *(const float4*)ap;
      ra[1] = *(const float4*)(ap + 4);
#pragma unroll
      for (int ch = 0; ch < 2; ++ch) {
        const float* wp =
            in_proj_w + (size_t)(c0 + (ch << 6) + srow) * DD + k0 + scol;
        rb[ch][0] = *(const float4*)wp;
        rb[ch][1] = *(const float4*)(wp + 4);
      }
    };
    auto WRITEL = [&](int buf) {
      *(bf16x8*)&As[buf][srow][scol] = cvt8(ra[0], ra[1]);
#pragma unroll
      for (int ch = 0; ch < 2; ++ch)
        *(bf16x8*)&Bs[buf][(ch << 6) + srow][scol] = cvt8(rb[ch][0], rb[ch][1]);
    };

    f32x4 acc[2][4];
#pragma unroll
    for (int m = 0; m < 2; ++m)
#pragma unroll
      for (int n = 0; n < 4; ++n) acc[m][n] = (f32x4){0.f, 0.f, 0.f, 0.f};

    int buf = 0;
    LOADR(0);
    WRITEL(0);
    __syncthreads();
    for (int kt = 0; kt < 8; ++kt) {
      if (kt + 1 < 8) LOADR(kt + 1);
      bf16x8 af[2], bfr[4];
#pragma unroll
      for (int m = 0; m < 2; ++m)
        af[m] = *(const bf16x8*)&As[buf][wr * 32 + (m << 4) + c][h8];
#pragma unroll
      for (int n = 0; n < 4; ++n)
        bfr[n] = *(const bf16x8*)&Bs[buf][(wc2 << 6) + (n << 4) + c][h8];
#pragma unroll
      for (int m = 0; m < 2; ++m)
#pragma unroll
        for (int n = 0; n < 4; ++n)
          acc[m][n] = __builtin_amdgcn_mfma_f32_16x16x32_bf16(af[m], bfr[n],
                                                              acc[m][n], 0, 0, 0);
      if (kt + 1 < 8) WRITEL(buf ^ 1);
      __syncthreads();
      buf ^= 1;
    }

    float bv[4];
#pragma unroll
    for (int n = 0; n < 4; ++n)
      bv[n] = in_proj_b[c0 + (wc2 << 6) + (n << 4) + c];
#pragma unroll
    for (int m = 0; m < 2; ++m)
#pragma unroll
      for (int i = 0; i < 4; ++i) {
        const int gr = r0 + wr * 32 + (m << 4) + (hq << 2) + i;
#pragma unroll
        for (int n = 0; n < 4; ++n)
          qkv_bf[(size_t)gr * 768 + c0 + (wc2 << 6) + (n << 4) + c] =
              (__hip_bfloat16)(acc[m][n][i] + bv[n]);
      }
  } else {
    if (tid == 0) { flag3f = 0; flagNA = 0; }
    if (tid < BB) cnt8[tid] = 0;
    __syncthreads();
    for (int i = tid; i < BB * LL; i += 256) {
      unsigned char v = mb[i];
      if (v) {
        if ((i & 3) == 3 && v == 0x3F) flag3f = 1;
        else if (i & 3) flagNA = 1;
      }
    }
    __syncthreads();
    const bool isfloat = (flag3f != 0);
    const bool isbool = (!isfloat) && (flagNA != 0);
    if (isbool) {
      for (int i = tid; i < BB * LL; i += 256)
        if (mb[i] == 0) atomicAdd(&cnt8[i >> 10], 1);
    } else {
      const int* mi = (const int*)mb;
      for (int i = tid; i < BB * LL; i += 256)
        if (mi[i] == 0) atomicAdd(&cnt8[i >> 10], 1);
    }
    __syncthreads();
    if (tid < BB) lens[tid] = cnt8[tid];
  }
}

// ---------------------------------------------------------------------------
// Shared GEMM body: C = A @ W^T + epi. 4 waves (2x2), BK=32, proven [row][32]
// layout. EPI: 1 = +bias,gelu -> bf16; 2 = +bias+resid(f32) -> f32 AND bf16.
// Dead M-tiles return (consumers skip / reduce zeroes padded rows).
// ---------------------------------------------------------------------------
template <int EPI, int BM, int BN>
__device__ __forceinline__ void gemm_body(
    const __hip_bfloat16* __restrict__ A, const __hip_bfloat16* __restrict__ W,
    const float* __restrict__ bias, const float* __restrict__ resid,
    float* __restrict__ Cf, __hip_bfloat16* __restrict__ Cb, const int N,
    const int K, const int* __restrict__ lens, const int bx, const int by) {
  constexpr int MF = BM / 32;
  constexpr int NF = BN / 32;
  constexpr int CHA = BM / 64;
  constexpr int CHB = BN / 64;
  __shared__ __bf16 As[2][BM][32];
  __shared__ __bf16 Bs[2][BN][32];

  const int tid = threadIdx.x;
  const int w = tid >> 6;
  const int lane = tid & 63;
  const int c = lane & 15;
  const int hq = lane >> 4;
  const int h8 = hq << 3;
  const int wr = w >> 1, wc = w & 1;
  const int c0 = bx * BN;
  const int r0 = by * BM;
  if ((r0 & (LL - 1)) >= lens[r0 >> 10]) return;  // dead tile

  const int srow = tid >> 2;
  const int scol = (tid & 3) << 3;

  auto STAGE = [&](int buf, int kt) {
    const int k0 = kt << 5;
#pragma unroll
    for (int ch = 0; ch < CHA; ++ch)
      gload16(A + (size_t)(r0 + (ch << 6) + srow) * K + k0 + scol,
              &As[buf][(ch << 6) + (w << 4)][0]);
#pragma unroll
    for (int ch = 0; ch < CHB; ++ch)
      gload16(W + (size_t)(c0 + (ch << 6) + srow) * K + k0 + scol,
              &Bs[buf][(ch << 6) + (w << 4)][0]);
  };

  f32x4 acc[MF][NF];
#pragma unroll
  for (int m = 0; m < MF; ++m)
#pragma unroll
    for (int n = 0; n < NF; ++n) acc[m][n] = (f32x4){0.f, 0.f, 0.f, 0.f};

  const int nkt = K >> 5;
  int buf = 0;
  STAGE(0, 0);
  __syncthreads();
  for (int kt = 0; kt < nkt; ++kt) {
    if (kt + 1 < nkt) STAGE(buf ^ 1, kt + 1);
    bf16x8 af[MF], bfr[NF];
#pragma unroll
    for (int m = 0; m < MF; ++m)
      af[m] = *(const bf16x8*)&As[buf][wr * (MF * 16) + (m << 4) + c][h8];
#pragma unroll
    for (int n = 0; n < NF; ++n)
      bfr[n] = *(const bf16x8*)&Bs[buf][wc * (NF * 16) + (n << 4) + c][h8];
#pragma unroll
    for (int m = 0; m < MF; ++m)
#pragma unroll
      for (int n = 0; n < NF; ++n)
        acc[m][n] =
            __builtin_amdgcn_mfma_f32_16x16x32_bf16(af[m], bfr[n], acc[m][n], 0, 0, 0);
    __syncthreads();
    buf ^= 1;
  }

  float bv[NF];
#pragma unroll
  for (int n = 0; n < NF; ++n) bv[n] = bias[c0 + wc * (NF * 16) + (n << 4) + c];

#pragma unroll
  for (int m = 0; m < MF; ++m) {
#pragma unroll
    for (int i = 0; i < 4; ++i) {
      const int gr = r0 + wr * (MF * 16) + (m << 4) + (hq << 2) + i;
#pragma unroll
      for (int n = 0; n < NF; ++n) {
        const int gc = c0 + wc * (NF * 16) + (n << 4) + c;
        float v = acc[m][n][i] + bv[n];
        if (EPI == 1) v = 0.5f * v * (1.0f + erff(v * 0.70710678118654752f));
        if (EPI == 2) {
          v += resid[(size_t)gr * N + gc];
          Cf[(size_t)gr * N + gc] = v;
        }
        Cb[(size_t)gr * N + gc] = (__hip_bfloat16)v;
      }
    }
  }
}

// ---------------------------------------------------------------------------
// K3: [0,512) proj tiles (EPI=2, 64x64) | [512,768) cvt ff1_w -> bf16
// ---------------------------------------------------------------------------
__global__ __launch_bounds__(256) void proj_cvt(
    const __hip_bfloat16* __restrict__ ctx, const __hip_bfloat16* __restrict__ wc,
    const float* __restrict__ bc, const float* __restrict__ src,
    float* __restrict__ hbuf_f, __hip_bfloat16* __restrict__ hbuf_bf,
    const int* __restrict__ lens, const float* __restrict__ ff1_w,
    __hip_bfloat16* __restrict__ wff1_bf) {
  const int bid = blockIdx.x;
  if (bid < 512) {
    gemm_body<2, 64, 64>(ctx, wc, bc, src, hbuf_f, hbuf_bf, DD, DD, lens,
                         bid & 3, bid >> 2);
  } else {
    cvt_block(ff1_w, wff1_bf, (bid - 512) * 2048);
  }
}

// ---------------------------------------------------------------------------
// K4: [0,1024) ff1 tiles (EPI=1, 128x128) | [1024,1280) cvt ff2_w -> bf16
// ---------------------------------------------------------------------------
__global__ __launch_bounds__(256) void ff1_cvt(
    const __hip_bfloat16* __restrict__ hbuf_bf,
    const __hip_bfloat16* __restrict__ wff1_bf, const float* __restrict__ ff1_b,
    __hip_bfloat16* __restrict__ ff1o_bf, const int* __restrict__ lens,
    const float* __restrict__ ff2_w, __hip_bfloat16* __restrict__ wff2_bf) {
  const int bid = blockIdx.x;
  if (bid < 1024) {
    gemm_body<1, 128, 128>(hbuf_bf, wff1_bf, ff1_b, nullptr, nullptr, ff1o_bf,
                           DFFN, DD, lens, bid & 15, bid >> 4);
  } else {
    cvt_block(ff2_w, wff2_bf, (bid - 1024) * 2048);
  }
}

// ---------------------------------------------------------------------------
// K5: FF2 split-K partial: P[z][M][256](bf16) = A[M, z*512:(z+1)*512] @ W^T.
// ---------------------------------------------------------------------------
__global__ __launch_bounds__(256) void gemm_ff2_part(
    const __hip_bfloat16* __restrict__ A, const __hip_bfloat16* __restrict__ W,
    __hip_bfloat16* __restrict__ P, const int* __restrict__ lens) {
  __shared__ __bf16 As[2][64][32];
  __shared__ __bf16 Bs[2][128][32];

  const int tid = threadIdx.x;
  const int w = tid >> 6;
  const int lane = tid & 63;
  const int c = lane & 15;
  const int hq = lane >> 4;
  const int h8 = hq << 3;
  const int wr = w >> 1, wc = w & 1;
  const int c0 = blockIdx.x << 7;
  const int r0 = blockIdx.y << 6;
  if ((r0 & (LL - 1)) >= lens[r0 >> 10]) return;

  const int kz = blockIdx.z;
  const int kbase = kz << 9;
  const int srow = tid >> 2;
  const int scol = (tid & 3) << 3;

  auto STAGE = [&](int buf, int kt) {
    const int k0 = kbase + (kt << 5);
    gload16(A + (size_t)(r0 + srow) * DFFN + k0 + scol, &As[buf][w << 4][0]);
#pragma unroll
    for (int ch = 0; ch < 2; ++ch)
      gload16(W + (size_t)(c0 + (ch << 6) + srow) * DFFN + k0 + scol,
              &Bs[buf][(ch << 6) + (w << 4)][0]);
  };

  f32x4 acc[2][4];
#pragma unroll
  for (int m = 0; m < 2; ++m)
#pragma unroll
    for (int n = 0; n < 4; ++n) acc[m][n] = (f32x4){0.f, 0.f, 0.f, 0.f};

  int buf = 0;
  STAGE(0, 0);
  __syncthreads();
  for (int kt = 0; kt < 16; ++kt) {
    if (kt + 1 < 16) STAGE(buf ^ 1, kt + 1);
    bf16x8 af[2], bfr[4];
#pragma unroll
    for (int m = 0; m < 2; ++m)
      af[m] = *(const bf16x8*)&As[buf][wr * 32 + (m << 4) + c][h8];
#pragma unroll
    for (int n = 0; n < 4; ++n)
      bfr[n] = *(const bf16x8*)&Bs[buf][(wc << 6) + (n << 4) + c][h8];
#pragma unroll
    for (int m = 0; m < 2; ++m)
#pragma unroll
      for (int n = 0; n < 4; ++n)
        acc[m][n] =
            __builtin_amdgcn_mfma_f32_16x16x32_bf16(af[m], bfr[n], acc[m][n], 0, 0, 0);
    __syncthreads();
    buf ^= 1;
  }

  __hip_bfloat16* Pz = P + (size_t)kz * (BB * LL) * DD;
#pragma unroll
  for (int m = 0; m < 2; ++m)
#pragma unroll
    for (int i = 0; i < 4; ++i) {
      const int gr = r0 + wr * 32 + (m << 4) + (hq << 2) + i;
#pragma unroll
      for (int n = 0; n < 4; ++n)
        Pz[(size_t)gr * DD + c0 + (wc << 6) + (n << 4) + c] =
            (__hip_bfloat16)acc[m][n][i];
    }
}

// ---------------------------------------------------------------------------
// K6: FF2 reduce: out = resid + bias + sum_z P[z] (bf16), zero padded rows.
// ---------------------------------------------------------------------------
__global__ __launch_bounds__(256) void ff2_reduce(
    const __hip_bfloat16* __restrict__ P, const float* __restrict__ resid,
    const float* __restrict__ bias, float* __restrict__ out,
    const int* __restrict__ lens) {
  const int idx = blockIdx.x * 256 + threadIdx.x;  // one float4
  const int r = idx >> 6;
  const int c4 = (idx & 63) << 2;
  float4 o;
  if ((r & (LL - 1)) >= lens[r >> 10]) {
    o.x = o.y = o.z = o.w = 0.f;
  } else {
    const size_t base = (size_t)r * DD + c4;
    o = *(const float4*)&resid[base];
    const float4 bv = *(const float4*)&bias[c4];
    o.x += bv.x; o.y += bv.y; o.z += bv.z; o.w += bv.w;
#pragma unroll
    for (int z = 0; z < 4; ++z) {
      const ushort4 pu = *(const ushort4*)(P + (size_t)z * (BB * LL) * DD + base);
      o.x += __bfloat162float(*(const __hip_bfloat16*)&pu.x);
      o.y += __bfloat162float(*(const __hip_bfloat16*)&pu.y);
      o.z += __bfloat162float(*(const __hip_bfloat16*)&pu.z);
      o.w += __bfloat162float(*(const __hip_bfloat16*)&pu.w);
    }
  }
  *(float4*)&out[(size_t)r * DD + c4] = o;
}

// ---------------------------------------------------------------------------
// K2: MFMA bf16 flash attention (unchanged, proven).
// ---------------------------------------------------------------------------
__global__ __launch_bounds__(256) void attn_fwd_mfma(
    const __hip_bfloat16* __restrict__ qkv, __hip_bfloat16* __restrict__ ctx,
    const int* __restrict__ lens) {
  __shared__ __bf16 Ks[2][64][56];
  __shared__ __bf16 Vt[2][32][66];
  __shared__ __bf16 Pl[4][16][72];

  const int tid = threadIdx.x;
  const int q0 = blockIdx.x << 6;
  const int hh = blockIdx.y;
  const int b = blockIdx.z;
  const int slen = lens[b];
  if (q0 >= slen) return;

  const int w = tid >> 6;
  const int lane = tid & 63;
  const int c = lane & 15;
  const int h = lane >> 4;
  const int h8 = h << 3;

  const float L2E = 1.44269504f;
  const float sf = (float)slen;
  const float cb = -7.0f * L2E;
  const float cd = (1.0f / sf) * L2E;
  const float qscale = 0.17677669529663689f * L2E;

  bf16x8 qf;
  {
    const int qrow = q0 + (w << 4) + c;
    const bf16x8 qraw =
        *(const bf16x8*)(qkv + (size_t)(b * LL + qrow) * 768 + hh * DHH + h8);
#pragma unroll
    for (int j = 0; j < 8; ++j) qf[j] = (__bf16)((float)qraw[j] * qscale);
  }

  f32x4 acc0 = {0.f, 0.f, 0.f, 0.f};
  f32x4 acc1 = {0.f, 0.f, 0.f, 0.f};
  float lsum[4] = {0.f, 0.f, 0.f, 0.f};

  const int skey = tid >> 2;
  const int sdg = (tid & 3) << 3;
  const int ntk = (slen + 63) >> 6;
  const int qg = q0 + (w << 4) + (h << 2);

  const __hip_bfloat16* kvbase = qkv + (size_t)b * LL * 768 + 256 + hh * DHH + sdg;

  bf16x8 kreg, vreg;
  {
    const __hip_bfloat16* kb = kvbase + (size_t)skey * 768;
    kreg = *(const bf16x8*)kb;
    vreg = *(const bf16x8*)(kb + 256);
    *(bf16x8*)&Ks[0][skey][sdg] = kreg;
#pragma unroll
    for (int j = 0; j < 8; ++j) Vt[0][sdg + j][skey] = vreg[j];
  }
  if (ntk > 1) {
    const __hip_bfloat16* kb = kvbase + (size_t)(64 + skey) * 768;
    kreg = *(const bf16x8*)kb;
    vreg = *(const bf16x8*)(kb + 256);
  }
  __syncthreads();

  for (int kt = 0; kt < ntk; ++kt) {
    const int p = kt & 1;
    const int kbase = kt << 6;

    f32x4 st[4];
    __builtin_amdgcn_s_setprio(1);
#pragma unroll
    for (int t = 0; t < 4; ++t) {
      const bf16x8 kf = *(const bf16x8*)&Ks[p][(t << 4) + c][h8];
      st[t] = __builtin_amdgcn_mfma_f32_16x16x32_bf16(
          qf, kf, (f32x4){0.f, 0.f, 0.f, 0.f}, 0, 0, 0);
    }
    __builtin_amdgcn_s_setprio(0);

    if (kbase + 64 <= slen) {
#pragma unroll
      for (int t = 0; t < 4; ++t) {
        const float kjf = (float)(kbase + (t << 4) + c);
#pragma unroll
        for (int i = 0; i < 4; ++i) {
          const float dist = fabsf((float)(qg + i) - kjf);
          const float pv = __builtin_amdgcn_exp2f(st[t][i] + cb - dist * cd);
          lsum[i] += pv;
          Pl[w][(h << 2) + i][c + (t << 4)] = (__bf16)pv;
        }
      }
    } else {
#pragma unroll
      for (int t = 0; t < 4; ++t) {
        const int kj = kbase + (t << 4) + c;
        const bool kvalid = kj < slen;
        const float kjf = (float)kj;
#pragma unroll
        for (int i = 0; i < 4; ++i) {
          const float dist = fabsf((float)(qg + i) - kjf);
          const float arg = kvalid ? (st[t][i] + cb - dist * cd) : -1e30f;
          const float pv = __builtin_amdgcn_exp2f(arg);
          lsum[i] += pv;
          Pl[w][(h << 2) + i][c + (t << 4)] = (__bf16)pv;
        }
      }
    }

    asm volatile("s_waitcnt lgkmcnt(0)" ::: "memory");

    __builtin_amdgcn_s_setprio(1);
#pragma unroll
    for (int n = 0; n < 2; ++n) {
      const bf16x8 pf = *(const bf16x8*)&Pl[w][c][h8 + (n << 5)];
      const uint32_t* v0p = (const uint32_t*)&Vt[p][c][h8 + (n << 5)];
      const uint32_t* v1p = (const uint32_t*)&Vt[p][16 + c][h8 + (n << 5)];
      union { uint32_t u[4]; bf16x8 v; } t0, t1;
#pragma unroll
      for (int j = 0; j < 4; ++j) { t0.u[j] = v0p[j]; t1.u[j] = v1p[j]; }
      acc0 = __builtin_amdgcn_mfma_f32_16x16x32_bf16(pf, t0.v, acc0, 0, 0, 0);
      acc1 = __builtin_amdgcn_mfma_f32_16x16x32_bf16(pf, t1.v, acc1, 0, 0, 0);
    }
    __builtin_amdgcn_s_setprio(0);

    if (kt + 1 < ntk) {
      *(bf16x8*)&Ks[p ^ 1][skey][sdg] = kreg;
#pragma unroll
      for (int j = 0; j < 8; ++j) Vt[p ^ 1][sdg + j][skey] = vreg[j];
      if (kt + 2 < ntk) {
        const __hip_bfloat16* kb = kvbase + (size_t)(((kt + 2) << 6) + skey) * 768;
        kreg = *(const bf16x8*)kb;
        vreg = *(const bf16x8*)(kb + 256);
      }
    }
    __syncthreads();
  }

#pragma unroll
  for (int i = 0; i < 4; ++i) {
    float l = lsum[i];
    l += __shfl_xor(l, 1);
    l += __shfl_xor(l, 2);
    l += __shfl_xor(l, 4);
    l += __shfl_xor(l, 8);
    const float il = 1.0f / l;
    __hip_bfloat16* op =
        ctx + (size_t)(b * LL + q0 + (w << 4) + (h << 2) + i) * 256 + hh * DHH;
    op[c] = (__hip_bfloat16)(acc0[i] * il);
    op[c + 16] = (__hip_bfloat16)(acc1[i] * il);
  }
}

// ---------------------------------------------------------------------------
extern "C" void kernel_launch(void* const* d_in, const int* in_sizes, int n_in,
                              void* d_out, int out_size, void* d_ws,
                              size_t ws_size, hipStream_t stream) {
  (void)in_sizes; (void)n_in; (void)out_size; (void)ws_size;
  const float* src = (const float*)d_in[0];
  const unsigned char* mask = (const unsigned char*)d_in[1];
  const float* in_proj_w = (const float*)d_in[2];
  const float* in_proj_b = (const float*)d_in[3];
  const float* out_w = (const float*)d_in[4];
  const float* out_b = (const float*)d_in[5];
  const float* proj_w = (const float*)d_in[6];
  const float* proj_b = (const float*)d_in[7];
  const float* ff1_w = (const float*)d_in[8];
  const float* ff1_b = (const float*)d_in[9];
  const float* ff2_w = (const float*)d_in[10];
  const float* ff2_b = (const float*)d_in[11];
  float* out = (float*)d_out;

  const int M = BB * LL;  // 8192
  char* p = (char*)d_ws;
  __hip_bfloat16* qkv_bf = (__hip_bfloat16*)p; p += (size_t)M * 768 * 2;
  __hip_bfloat16* ctx_bf = (__hip_bfloat16*)p; p += (size_t)M * 256 * 2;
  float* hbuf_f = (float*)p;                    p += (size_t)M * 256 * 4;
  __hip_bfloat16* hbuf_bf = (__hip_bfloat16*)p; p += (size_t)M * 256 * 2;
  __hip_bfloat16* ff1o_bf = (__hip_bfloat16*)p; p += (size_t)M * 2048 * 2;
  __hip_bfloat16* wff1_bf = (__hip_bfloat16*)p; p += (size_t)2048 * 256 * 2;
  __hip_bfloat16* wff2_bf = (__hip_bfloat16*)p; p += (size_t)256 * 2048 * 2;
  __hip_bfloat16* wc_bf = (__hip_bfloat16*)p;   p += (size_t)256 * 256 * 2;
  float* bc = (float*)p;                        p += 256 * 4;
  int* lens = (int*)p;                          p += 256;
  __hip_bfloat16* pbuf = (__hip_bfloat16*)p;    p += (size_t)4 * M * 256 * 2;

  // K1: Wc first (longest serial chain), then QKV tiles, lens
  fused_pre_qkv<<<NB_K1, 256, 0, stream>>>(src, mask, in_proj_w, in_proj_b,
                                           proj_w, out_w, proj_b, out_b,
                                           qkv_bf, wc_bf, bc, lens);

  // K2: attention
  attn_fwd_mfma<<<dim3(LL / 64, HHN, BB), 256, 0, stream>>>(qkv_bf, ctx_bf, lens);

  // K3: proj tiles + ff1_w cvt (cvt completes before K4 by stream order)
  proj_cvt<<<768, 256, 0, stream>>>(ctx_bf, wc_bf, bc, src, hbuf_f, hbuf_bf,
                                    lens, ff1_w, wff1_bf);

  // K4: ff1 tiles + ff2_w cvt (cvt completes before K5)
  ff1_cvt<<<1280, 256, 0, stream>>>(hbuf_bf, wff1_bf, ff1_b, ff1o_bf, lens,
                                    ff2_w, wff2_bf);

  // K5: FF2 split-K x4 bf16 partials
  gemm_ff2_part<<<dim3(2, 128, 4), 256, 0, stream>>>(ff1o_bf, wff2_bf, pbuf, lens);

  // K6: out = hbuf + sum partials + bias, zero padded rows
  ff2_reduce<<<M * 256 / 4 / 256, 256, 0, stream>>>(pbuf, hbuf_f, ff2_b, out, lens);
}

// Round 15
// 107.492 us; speedup vs baseline: 1.3888x; 1.0759x over previous
//
#include <hip/hip_runtime.h>
#include <hip/hip_bf16.h>

// DeepPM Transformer encoder layer (round 15): 6-kernel pipeline.
// Round-14 was flat (114-117us band): per-kernel work no longer dominates.
// This round: (1) hbuf kept bf16-only (residual read in K6 is bf16; -16MB
// traffic), (2) XCD-aware chunked tile swizzle (T1) on all GEMM grids so each
// XCD's private L2 serves its blocks' shared W/A panels, (3) FF2-part grid
// flattened for the swizzle (z-slices grouped per XCD).
//  K1 [wc|qkv|lens]  K2 attn  K3 [proj|cvt ff1_w]  K4 [ff1|cvt ff2_w]
//  K5 ff2 split-K x4  K6 ff2 reduce
// B=8, L=1024, D=256, H=8 (DH=32), DFF=2048.

#define BB   8
#define LL   1024
#define DD   256
#define HHN  8
#define DHH  32
#define DFFN 2048

typedef __attribute__((ext_vector_type(8))) __bf16 bf16x8;
typedef __attribute__((ext_vector_type(4))) float f32x4;

__device__ inline void gload16(const void* g, void* l) {
  __builtin_amdgcn_global_load_lds(
      (const __attribute__((address_space(1))) void*)g,
      (__attribute__((address_space(3))) void*)l, 16, 0, 0);
}

__device__ inline bf16x8 cvt8(const float4 a, const float4 b) {
  bf16x8 o;
  o[0] = (__bf16)a.x; o[1] = (__bf16)a.y; o[2] = (__bf16)a.z; o[3] = (__bf16)a.w;
  o[4] = (__bf16)b.x; o[5] = (__bf16)b.y; o[6] = (__bf16)b.z; o[7] = (__bf16)b.w;
  return o;
}

// 256-thread block converts 2048 fp32 -> bf16 at element offset i0.
__device__ inline void cvt_block(const float* __restrict__ s,
                                 __hip_bfloat16* __restrict__ d, int i0) {
  const int i = i0 + threadIdx.x * 8;
  const float4 a = *(const float4*)(s + i);
  const float4 b = *(const float4*)(s + i + 4);
  *(bf16x8*)(d + i) = cvt8(a, b);
}

// XCD-chunked bijective swizzle (T1): nwg % 8 == 0 required.
__device__ inline int xcd_swz(int bid, int nwg) {
  return (bid & 7) * (nwg >> 3) + (bid >> 3);
}

// ---------------------------------------------------------------------------
// K1: Wc + QKV + lens.
//  [0,128):    Wc = proj_w@out_w (2 rows/block, LDS-staged, unroll-8), bc
//  [128,896):  QKV tile (BM=64 x BN=128), fp32 in (fused cvt), bf16 out,
//              XCD-swizzled tile map
//  896:        lens[b] from mask
// ---------------------------------------------------------------------------
#define NB_WC   128
#define NB_QKV  768
#define BID_QKV  NB_WC               // 128
#define BID_LENS (NB_WC + NB_QKV)    // 896
#define NB_K1    (BID_LENS + 1)      // 897

__global__ __launch_bounds__(256) void fused_pre_qkv(
    const float* __restrict__ src, const unsigned char* __restrict__ mb,
    const float* __restrict__ in_proj_w, const float* __restrict__ in_proj_b,
    const float* __restrict__ proj_w, const float* __restrict__ out_w,
    const float* __restrict__ proj_b, const float* __restrict__ out_b,
    __hip_bfloat16* __restrict__ qkv_bf, __hip_bfloat16* __restrict__ wc_bf,
    float* __restrict__ bc, int* __restrict__ lens) {
  __shared__ __bf16 As[2][64][32];
  __shared__ __bf16 Bs[2][128][32];
  __shared__ float red[256];
  __shared__ float pw[2][256];
  __shared__ int cnt8[BB];
  __shared__ int flag3f, flagNA;

  const int bid = blockIdx.x;
  const int tid = threadIdx.x;

  if (bid < NB_WC) {
    const int i0 = bid << 1;
    const int k = tid;
    pw[0][k] = proj_w[(size_t)i0 * DD + k];
    pw[1][k] = proj_w[(size_t)(i0 + 1) * DD + k];
    __syncthreads();
    float a0 = 0.f, a1 = 0.f;
#pragma unroll 8
    for (int n = 0; n < DD; ++n) {
      const float won = out_w[n * DD + k];
      a0 = fmaf(pw[0][n], won, a0);
      a1 = fmaf(pw[1][n], won, a1);
    }
    wc_bf[(size_t)i0 * DD + k] = (__hip_bfloat16)a0;
    wc_bf[(size_t)(i0 + 1) * DD + k] = (__hip_bfloat16)a1;
#pragma unroll
    for (int j = 0; j < 2; ++j) {
      red[k] = pw[j][k] * out_b[k];
      __syncthreads();
      for (int sft = 128; sft > 0; sft >>= 1) {
        if (k < sft) red[k] += red[k + sft];
        __syncthreads();
      }
      if (k == 0) bc[i0 + j] = proj_b[i0 + j] + red[0];
      __syncthreads();
    }
  } else if (bid < BID_LENS) {
    const int qb = xcd_swz(bid - BID_QKV, NB_QKV);
    const int x = qb % 6;
    const int y = qb / 6;
    const int c0 = x << 7;
    const int r0 = y << 6;
    const int w = tid >> 6;
    const int lane = tid & 63;
    const int c = lane & 15;
    const int hq = lane >> 4;
    const int h8 = hq << 3;
    const int wr = w >> 1, wc2 = w & 1;
    const int srow = tid >> 2;
    const int scol = (tid & 3) << 3;

    float4 ra[2], rb[2][2];
    auto LOADR = [&](int kt) {
      const int k0 = kt << 5;
      const float* ap = src + (size_t)(r0 + srow) * DD + k0 + scol;
      ra[0] = *(const float4*)ap;
      ra[1] = *(const float4*)(ap + 4);
#pragma unroll
      for (int ch = 0; ch < 2; ++ch) {
        const float* wp =
            in_proj_w + (size_t)(c0 + (ch << 6) + srow) * DD + k0 + scol;
        rb[ch][0] = *(const float4*)wp;
        rb[ch][1] = *(const float4*)(wp + 4);
      }
    };
    auto WRITEL = [&](int buf) {
      *(bf16x8*)&As[buf][srow][scol] = cvt8(ra[0], ra[1]);
#pragma unroll
      for (int ch = 0; ch < 2; ++ch)
        *(bf16x8*)&Bs[buf][(ch << 6) + srow][scol] = cvt8(rb[ch][0], rb[ch][1]);
    };

    f32x4 acc[2][4];
#pragma unroll
    for (int m = 0; m < 2; ++m)
#pragma unroll
      for (int n = 0; n < 4; ++n) acc[m][n] = (f32x4){0.f, 0.f, 0.f, 0.f};

    int buf = 0;
    LOADR(0);
    WRITEL(0);
    __syncthreads();
    for (int kt = 0; kt < 8; ++kt) {
      if (kt + 1 < 8) LOADR(kt + 1);
      bf16x8 af[2], bfr[4];
#pragma unroll
      for (int m = 0; m < 2; ++m)
        af[m] = *(const bf16x8*)&As[buf][wr * 32 + (m << 4) + c][h8];
#pragma unroll
      for (int n = 0; n < 4; ++n)
        bfr[n] = *(const bf16x8*)&Bs[buf][(wc2 << 6) + (n << 4) + c][h8];
#pragma unroll
      for (int m = 0; m < 2; ++m)
#pragma unroll
        for (int n = 0; n < 4; ++n)
          acc[m][n] = __builtin_amdgcn_mfma_f32_16x16x32_bf16(af[m], bfr[n],
                                                              acc[m][n], 0, 0, 0);
      if (kt + 1 < 8) WRITEL(buf ^ 1);
      __syncthreads();
      buf ^= 1;
    }

    float bv[4];
#pragma unroll
    for (int n = 0; n < 4; ++n)
      bv[n] = in_proj_b[c0 + (wc2 << 6) + (n << 4) + c];
#pragma unroll
    for (int m = 0; m < 2; ++m)
#pragma unroll
      for (int i = 0; i < 4; ++i) {
        const int gr = r0 + wr * 32 + (m << 4) + (hq << 2) + i;
#pragma unroll
        for (int n = 0; n < 4; ++n)
          qkv_bf[(size_t)gr * 768 + c0 + (wc2 << 6) + (n << 4) + c] =
              (__hip_bfloat16)(acc[m][n][i] + bv[n]);
      }
  } else {
    if (tid == 0) { flag3f = 0; flagNA = 0; }
    if (tid < BB) cnt8[tid] = 0;
    __syncthreads();
    for (int i = tid; i < BB * LL; i += 256) {
      unsigned char v = mb[i];
      if (v) {
        if ((i & 3) == 3 && v == 0x3F) flag3f = 1;
        else if (i & 3) flagNA = 1;
      }
    }
    __syncthreads();
    const bool isfloat = (flag3f != 0);
    const bool isbool = (!isfloat) && (flagNA != 0);
    if (isbool) {
      for (int i = tid; i < BB * LL; i += 256)
        if (mb[i] == 0) atomicAdd(&cnt8[i >> 10], 1);
    } else {
      const int* mi = (const int*)mb;
      for (int i = tid; i < BB * LL; i += 256)
        if (mi[i] == 0) atomicAdd(&cnt8[i >> 10], 1);
    }
    __syncthreads();
    if (tid < BB) lens[tid] = cnt8[tid];
  }
}

// ---------------------------------------------------------------------------
// Shared GEMM body: C = A @ W^T + epi. 4 waves (2x2), BK=32, [row][32] layout.
// EPI: 1 = +bias,gelu -> bf16; 2 = +bias+resid(f32) -> bf16 only.
// ---------------------------------------------------------------------------
template <int EPI, int BM, int BN>
__device__ __forceinline__ void gemm_body(
    const __hip_bfloat16* __restrict__ A, const __hip_bfloat16* __restrict__ W,
    const float* __restrict__ bias, const float* __restrict__ resid,
    __hip_bfloat16* __restrict__ Cb, const int N, const int K,
    const int* __restrict__ lens, const int bx, const int by) {
  constexpr int MF = BM / 32;
  constexpr int NF = BN / 32;
  constexpr int CHA = BM / 64;
  constexpr int CHB = BN / 64;
  __shared__ __bf16 As[2][BM][32];
  __shared__ __bf16 Bs[2][BN][32];

  const int tid = threadIdx.x;
  const int w = tid >> 6;
  const int lane = tid & 63;
  const int c = lane & 15;
  const int hq = lane >> 4;
  const int h8 = hq << 3;
  const int wr = w >> 1, wc = w & 1;
  const int c0 = bx * BN;
  const int r0 = by * BM;
  if ((r0 & (LL - 1)) >= lens[r0 >> 10]) return;  // dead tile

  const int srow = tid >> 2;
  const int scol = (tid & 3) << 3;

  auto STAGE = [&](int buf, int kt) {
    const int k0 = kt << 5;
#pragma unroll
    for (int ch = 0; ch < CHA; ++ch)
      gload16(A + (size_t)(r0 + (ch << 6) + srow) * K + k0 + scol,
              &As[buf][(ch << 6) + (w << 4)][0]);
#pragma unroll
    for (int ch = 0; ch < CHB; ++ch)
      gload16(W + (size_t)(c0 + (ch << 6) + srow) * K + k0 + scol,
              &Bs[buf][(ch << 6) + (w << 4)][0]);
  };

  f32x4 acc[MF][NF];
#pragma unroll
  for (int m = 0; m < MF; ++m)
#pragma unroll
    for (int n = 0; n < NF; ++n) acc[m][n] = (f32x4){0.f, 0.f, 0.f, 0.f};

  const int nkt = K >> 5;
  int buf = 0;
  STAGE(0, 0);
  __syncthreads();
  for (int kt = 0; kt < nkt; ++kt) {
    if (kt + 1 < nkt) STAGE(buf ^ 1, kt + 1);
    bf16x8 af[MF], bfr[NF];
#pragma unroll
    for (int m = 0; m < MF; ++m)
      af[m] = *(const bf16x8*)&As[buf][wr * (MF * 16) + (m << 4) + c][h8];
#pragma unroll
    for (int n = 0; n < NF; ++n)
      bfr[n] = *(const bf16x8*)&Bs[buf][wc * (NF * 16) + (n << 4) + c][h8];
#pragma unroll
    for (int m = 0; m < MF; ++m)
#pragma unroll
      for (int n = 0; n < NF; ++n)
        acc[m][n] =
            __builtin_amdgcn_mfma_f32_16x16x32_bf16(af[m], bfr[n], acc[m][n], 0, 0, 0);
    __syncthreads();
    buf ^= 1;
  }

  float bv[NF];
#pragma unroll
  for (int n = 0; n < NF; ++n) bv[n] = bias[c0 + wc * (NF * 16) + (n << 4) + c];

#pragma unroll
  for (int m = 0; m < MF; ++m) {
#pragma unroll
    for (int i = 0; i < 4; ++i) {
      const int gr = r0 + wr * (MF * 16) + (m << 4) + (hq << 2) + i;
#pragma unroll
      for (int n = 0; n < NF; ++n) {
        const int gc = c0 + wc * (NF * 16) + (n << 4) + c;
        float v = acc[m][n][i] + bv[n];
        if (EPI == 1) v = 0.5f * v * (1.0f + erff(v * 0.70710678118654752f));
        if (EPI == 2) v += resid[(size_t)gr * N + gc];
        Cb[(size_t)gr * N + gc] = (__hip_bfloat16)v;
      }
    }
  }
}

// ---------------------------------------------------------------------------
// K3: [0,512) proj tiles (EPI=2, 64x64, XCD-swizzled) | [512,768) cvt ff1_w
// ---------------------------------------------------------------------------
__global__ __launch_bounds__(256) void proj_cvt(
    const __hip_bfloat16* __restrict__ ctx, const __hip_bfloat16* __restrict__ wc,
    const float* __restrict__ bc, const float* __restrict__ src,
    __hip_bfloat16* __restrict__ hbuf_bf, const int* __restrict__ lens,
    const float* __restrict__ ff1_w, __hip_bfloat16* __restrict__ wff1_bf) {
  const int bid = blockIdx.x;
  if (bid < 512) {
    const int t = xcd_swz(bid, 512);
    gemm_body<2, 64, 64>(ctx, wc, bc, src, hbuf_bf, DD, DD, lens, t & 3, t >> 2);
  } else {
    cvt_block(ff1_w, wff1_bf, (bid - 512) * 2048);
  }
}

// ---------------------------------------------------------------------------
// K4: [0,1024) ff1 tiles (EPI=1, 128x128, XCD-swizzled) | [1024,1280) cvt ff2_w
// ---------------------------------------------------------------------------
__global__ __launch_bounds__(256) void ff1_cvt(
    const __hip_bfloat16* __restrict__ hbuf_bf,
    const __hip_bfloat16* __restrict__ wff1_bf, const float* __restrict__ ff1_b,
    __hip_bfloat16* __restrict__ ff1o_bf, const int* __restrict__ lens,
    const float* __restrict__ ff2_w, __hip_bfloat16* __restrict__ wff2_bf) {
  const int bid = blockIdx.x;
  if (bid < 1024) {
    const int t = xcd_swz(bid, 1024);
    gemm_body<1, 128, 128>(hbuf_bf, wff1_bf, ff1_b, nullptr, ff1o_bf, DFFN, DD,
                           lens, t & 15, t >> 4);
  } else {
    cvt_block(ff2_w, wff2_bf, (bid - 1024) * 2048);
  }
}

// ---------------------------------------------------------------------------
// K5: FF2 split-K partial: P[z][M][256](bf16) = A[M, z*512:(z+1)*512] @ W^T.
// 1D grid (1024), XCD-swizzled: each XCD gets a contiguous half z-slice
// (shares the W k-slice and A rows in its L2).
// tile t: z = t>>8, y = (t&255)>>1, x = t&1.
// ---------------------------------------------------------------------------
__global__ __launch_bounds__(256) void gemm_ff2_part(
    const __hip_bfloat16* __restrict__ A, const __hip_bfloat16* __restrict__ W,
    __hip_bfloat16* __restrict__ P, const int* __restrict__ lens) {
  __shared__ __bf16 As[2][64][32];
  __shared__ __bf16 Bs[2][128][32];

  const int t = xcd_swz(blockIdx.x, 1024);
  const int kz = t >> 8;
  const int y = (t & 255) >> 1;
  const int x = t & 1;

  const int tid = threadIdx.x;
  const int w = tid >> 6;
  const int lane = tid & 63;
  const int c = lane & 15;
  const int hq = lane >> 4;
  const int h8 = hq << 3;
  const int wr = w >> 1, wc = w & 1;
  const int c0 = x << 7;
  const int r0 = y << 6;
  if ((r0 & (LL - 1)) >= lens[r0 >> 10]) return;

  const int kbase = kz << 9;
  const int srow = tid >> 2;
  const int scol = (tid & 3) << 3;

  auto STAGE = [&](int buf, int kt) {
    const int k0 = kbase + (kt << 5);
    gload16(A + (size_t)(r0 + srow) * DFFN + k0 + scol, &As[buf][w << 4][0]);
#pragma unroll
    for (int ch = 0; ch < 2; ++ch)
      gload16(W + (size_t)(c0 + (ch << 6) + srow) * DFFN + k0 + scol,
              &Bs[buf][(ch << 6) + (w << 4)][0]);
  };

  f32x4 acc[2][4];
#pragma unroll
  for (int m = 0; m < 2; ++m)
#pragma unroll
    for (int n = 0; n < 4; ++n) acc[m][n] = (f32x4){0.f, 0.f, 0.f, 0.f};

  int buf = 0;
  STAGE(0, 0);
  __syncthreads();
  for (int kt = 0; kt < 16; ++kt) {
    if (kt + 1 < 16) STAGE(buf ^ 1, kt + 1);
    bf16x8 af[2], bfr[4];
#pragma unroll
    for (int m = 0; m < 2; ++m)
      af[m] = *(const bf16x8*)&As[buf][wr * 32 + (m << 4) + c][h8];
#pragma unroll
    for (int n = 0; n < 4; ++n)
      bfr[n] = *(const bf16x8*)&Bs[buf][(wc << 6) + (n << 4) + c][h8];
#pragma unroll
    for (int m = 0; m < 2; ++m)
#pragma unroll
      for (int n = 0; n < 4; ++n)
        acc[m][n] =
            __builtin_amdgcn_mfma_f32_16x16x32_bf16(af[m], bfr[n], acc[m][n], 0, 0, 0);
    __syncthreads();
    buf ^= 1;
  }

  __hip_bfloat16* Pz = P + (size_t)kz * (BB * LL) * DD;
#pragma unroll
  for (int m = 0; m < 2; ++m)
#pragma unroll
    for (int i = 0; i < 4; ++i) {
      const int gr = r0 + wr * 32 + (m << 4) + (hq << 2) + i;
#pragma unroll
      for (int n = 0; n < 4; ++n)
        Pz[(size_t)gr * DD + c0 + (wc << 6) + (n << 4) + c] =
            (__hip_bfloat16)acc[m][n][i];
    }
}

// ---------------------------------------------------------------------------
// K6: FF2 reduce: out = resid(bf16) + bias + sum_z P[z] (bf16), zero pad rows.
// ---------------------------------------------------------------------------
__global__ __launch_bounds__(256) void ff2_reduce(
    const __hip_bfloat16* __restrict__ P, const __hip_bfloat16* __restrict__ resid,
    const float* __restrict__ bias, float* __restrict__ out,
    const int* __restrict__ lens) {
  const int idx = blockIdx.x * 256 + threadIdx.x;  // one float4
  const int r = idx >> 6;
  const int c4 = (idx & 63) << 2;
  float4 o;
  if ((r & (LL - 1)) >= lens[r >> 10]) {
    o.x = o.y = o.z = o.w = 0.f;
  } else {
    const size_t base = (size_t)r * DD + c4;
    const ushort4 rv = *(const ushort4*)(resid + base);
    const float4 bv = *(const float4*)&bias[c4];
    o.x = __bfloat162float(*(const __hip_bfloat16*)&rv.x) + bv.x;
    o.y = __bfloat162float(*(const __hip_bfloat16*)&rv.y) + bv.y;
    o.z = __bfloat162float(*(const __hip_bfloat16*)&rv.z) + bv.z;
    o.w = __bfloat162float(*(const __hip_bfloat16*)&rv.w) + bv.w;
#pragma unroll
    for (int z = 0; z < 4; ++z) {
      const ushort4 pu = *(const ushort4*)(P + (size_t)z * (BB * LL) * DD + base);
      o.x += __bfloat162float(*(const __hip_bfloat16*)&pu.x);
      o.y += __bfloat162float(*(const __hip_bfloat16*)&pu.y);
      o.z += __bfloat162float(*(const __hip_bfloat16*)&pu.z);
      o.w += __bfloat162float(*(const __hip_bfloat16*)&pu.w);
    }
  }
  *(float4*)&out[(size_t)r * DD + c4] = o;
}

// ---------------------------------------------------------------------------
// K2: MFMA bf16 flash attention (unchanged, proven).
// ---------------------------------------------------------------------------
__global__ __launch_bounds__(256) void attn_fwd_mfma(
    const __hip_bfloat16* __restrict__ qkv, __hip_bfloat16* __restrict__ ctx,
    const int* __restrict__ lens) {
  __shared__ __bf16 Ks[2][64][56];
  __shared__ __bf16 Vt[2][32][66];
  __shared__ __bf16 Pl[4][16][72];

  const int tid = threadIdx.x;
  const int q0 = blockIdx.x << 6;
  const int hh = blockIdx.y;
  const int b = blockIdx.z;
  const int slen = lens[b];
  if (q0 >= slen) return;

  const int w = tid >> 6;
  const int lane = tid & 63;
  const int c = lane & 15;
  const int h = lane >> 4;
  const int h8 = h << 3;

  const float L2E = 1.44269504f;
  const float sf = (float)slen;
  const float cb = -7.0f * L2E;
  const float cd = (1.0f / sf) * L2E;
  const float qscale = 0.17677669529663689f * L2E;

  bf16x8 qf;
  {
    const int qrow = q0 + (w << 4) + c;
    const bf16x8 qraw =
        *(const bf16x8*)(qkv + (size_t)(b * LL + qrow) * 768 + hh * DHH + h8);
#pragma unroll
    for (int j = 0; j < 8; ++j) qf[j] = (__bf16)((float)qraw[j] * qscale);
  }

  f32x4 acc0 = {0.f, 0.f, 0.f, 0.f};
  f32x4 acc1 = {0.f, 0.f, 0.f, 0.f};
  float lsum[4] = {0.f, 0.f, 0.f, 0.f};

  const int skey = tid >> 2;
  const int sdg = (tid & 3) << 3;
  const int ntk = (slen + 63) >> 6;
  const int qg = q0 + (w << 4) + (h << 2);

  const __hip_bfloat16* kvbase = qkv + (size_t)b * LL * 768 + 256 + hh * DHH + sdg;

  bf16x8 kreg, vreg;
  {
    const __hip_bfloat16* kb = kvbase + (size_t)skey * 768;
    kreg = *(const bf16x8*)kb;
    vreg = *(const bf16x8*)(kb + 256);
    *(bf16x8*)&Ks[0][skey][sdg] = kreg;
#pragma unroll
    for (int j = 0; j < 8; ++j) Vt[0][sdg + j][skey] = vreg[j];
  }
  if (ntk > 1) {
    const __hip_bfloat16* kb = kvbase + (size_t)(64 + skey) * 768;
    kreg = *(const bf16x8*)kb;
    vreg = *(const bf16x8*)(kb + 256);
  }
  __syncthreads();

  for (int kt = 0; kt < ntk; ++kt) {
    const int p = kt & 1;
    const int kbase = kt << 6;

    f32x4 st[4];
    __builtin_amdgcn_s_setprio(1);
#pragma unroll
    for (int t = 0; t < 4; ++t) {
      const bf16x8 kf = *(const bf16x8*)&Ks[p][(t << 4) + c][h8];
      st[t] = __builtin_amdgcn_mfma_f32_16x16x32_bf16(
          qf, kf, (f32x4){0.f, 0.f, 0.f, 0.f}, 0, 0, 0);
    }
    __builtin_amdgcn_s_setprio(0);

    if (kbase + 64 <= slen) {
#pragma unroll
      for (int t = 0; t < 4; ++t) {
        const float kjf = (float)(kbase + (t << 4) + c);
#pragma unroll
        for (int i = 0; i < 4; ++i) {
          const float dist = fabsf((float)(qg + i) - kjf);
          const float pv = __builtin_amdgcn_exp2f(st[t][i] + cb - dist * cd);
          lsum[i] += pv;
          Pl[w][(h << 2) + i][c + (t << 4)] = (__bf16)pv;
        }
      }
    } else {
#pragma unroll
      for (int t = 0; t < 4; ++t) {
        const int kj = kbase + (t << 4) + c;
        const bool kvalid = kj < slen;
        const float kjf = (float)kj;
#pragma unroll
        for (int i = 0; i < 4; ++i) {
          const float dist = fabsf((float)(qg + i) - kjf);
          const float arg = kvalid ? (st[t][i] + cb - dist * cd) : -1e30f;
          const float pv = __builtin_amdgcn_exp2f(arg);
          lsum[i] += pv;
          Pl[w][(h << 2) + i][c + (t << 4)] = (__bf16)pv;
        }
      }
    }

    asm volatile("s_waitcnt lgkmcnt(0)" ::: "memory");

    __builtin_amdgcn_s_setprio(1);
#pragma unroll
    for (int n = 0; n < 2; ++n) {
      const bf16x8 pf = *(const bf16x8*)&Pl[w][c][h8 + (n << 5)];
      const uint32_t* v0p = (const uint32_t*)&Vt[p][c][h8 + (n << 5)];
      const uint32_t* v1p = (const uint32_t*)&Vt[p][16 + c][h8 + (n << 5)];
      union { uint32_t u[4]; bf16x8 v; } t0, t1;
#pragma unroll
      for (int j = 0; j < 4; ++j) { t0.u[j] = v0p[j]; t1.u[j] = v1p[j]; }
      acc0 = __builtin_amdgcn_mfma_f32_16x16x32_bf16(pf, t0.v, acc0, 0, 0, 0);
      acc1 = __builtin_amdgcn_mfma_f32_16x16x32_bf16(pf, t1.v, acc1, 0, 0, 0);
    }
    __builtin_amdgcn_s_setprio(0);

    if (kt + 1 < ntk) {
      *(bf16x8*)&Ks[p ^ 1][skey][sdg] = kreg;
#pragma unroll
      for (int j = 0; j < 8; ++j) Vt[p ^ 1][sdg + j][skey] = vreg[j];
      if (kt + 2 < ntk) {
        const __hip_bfloat16* kb = kvbase + (size_t)(((kt + 2) << 6) + skey) * 768;
        kreg = *(const bf16x8*)kb;
        vreg = *(const bf16x8*)(kb + 256);
      }
    }
    __syncthreads();
  }

#pragma unroll
  for (int i = 0; i < 4; ++i) {
    float l = lsum[i];
    l += __shfl_xor(l, 1);
    l += __shfl_xor(l, 2);
    l += __shfl_xor(l, 4);
    l += __shfl_xor(l, 8);
    const float il = 1.0f / l;
    __hip_bfloat16* op =
        ctx + (size_t)(b * LL + q0 + (w << 4) + (h << 2) + i) * 256 + hh * DHH;
    op[c] = (__hip_bfloat16)(acc0[i] * il);
    op[c + 16] = (__hip_bfloat16)(acc1[i] * il);
  }
}

// ---------------------------------------------------------------------------
extern "C" void kernel_launch(void* const* d_in, const int* in_sizes, int n_in,
                              void* d_out, int out_size, void* d_ws,
                              size_t ws_size, hipStream_t stream) {
  (void)in_sizes; (void)n_in; (void)out_size; (void)ws_size;
  const float* src = (const float*)d_in[0];
  const unsigned char* mask = (const unsigned char*)d_in[1];
  const float* in_proj_w = (const float*)d_in[2];
  const float* in_proj_b = (const float*)d_in[3];
  const float* out_w = (const float*)d_in[4];
  const float* out_b = (const float*)d_in[5];
  const float* proj_w = (const float*)d_in[6];
  const float* proj_b = (const float*)d_in[7];
  const float* ff1_w = (const float*)d_in[8];
  const float* ff1_b = (const float*)d_in[9];
  const float* ff2_w = (const float*)d_in[10];
  const float* ff2_b = (const float*)d_in[11];
  float* out = (float*)d_out;

  const int M = BB * LL;  // 8192
  char* p = (char*)d_ws;
  __hip_bfloat16* qkv_bf = (__hip_bfloat16*)p; p += (size_t)M * 768 * 2;
  __hip_bfloat16* ctx_bf = (__hip_bfloat16*)p; p += (size_t)M * 256 * 2;
  __hip_bfloat16* hbuf_bf = (__hip_bfloat16*)p; p += (size_t)M * 256 * 2;
  __hip_bfloat16* ff1o_bf = (__hip_bfloat16*)p; p += (size_t)M * 2048 * 2;
  __hip_bfloat16* wff1_bf = (__hip_bfloat16*)p; p += (size_t)2048 * 256 * 2;
  __hip_bfloat16* wff2_bf = (__hip_bfloat16*)p; p += (size_t)256 * 2048 * 2;
  __hip_bfloat16* wc_bf = (__hip_bfloat16*)p;   p += (size_t)256 * 256 * 2;
  float* bc = (float*)p;                        p += 256 * 4;
  int* lens = (int*)p;                          p += 256;
  __hip_bfloat16* pbuf = (__hip_bfloat16*)p;    p += (size_t)4 * M * 256 * 2;

  // K1: Wc first (longest serial chain), then QKV tiles (XCD-swizzled), lens
  fused_pre_qkv<<<NB_K1, 256, 0, stream>>>(src, mask, in_proj_w, in_proj_b,
                                           proj_w, out_w, proj_b, out_b,
                                           qkv_bf, wc_bf, bc, lens);

  // K2: attention
  attn_fwd_mfma<<<dim3(LL / 64, HHN, BB), 256, 0, stream>>>(qkv_bf, ctx_bf, lens);

  // K3: proj tiles (XCD-swizzled) + ff1_w cvt
  proj_cvt<<<768, 256, 0, stream>>>(ctx_bf, wc_bf, bc, src, hbuf_bf, lens,
                                    ff1_w, wff1_bf);

  // K4: ff1 tiles (XCD-swizzled) + ff2_w cvt
  ff1_cvt<<<1280, 256, 0, stream>>>(hbuf_bf, wff1_bf, ff1_b, ff1o_bf, lens,
                                    ff2_w, wff2_bf);

  // K5: FF2 split-K x4 bf16 partials (XCD-swizzled z-slices)
  gemm_ff2_part<<<1024, 256, 0, stream>>>(ff1o_bf, wff2_bf, pbuf, lens);

  // K6: out = hbuf(bf16) + sum partials + bias, zero padded rows
  ff2_reduce<<<M * 256 / 4 / 256, 256, 0, stream>>>(pbuf, hbuf_bf, ff2_b, out,
                                                    lens);
}